// Round 15
// baseline (398.894 us; speedup 1.0000x reference)
//
#include <hip/hip_runtime.h>
#include <hip/hip_bf16.h>

#define NN 6144
#define FEATN 128
#define INSM 512
#define HIDN 256
#define DOUT 64

typedef _Float16 h4v __attribute__((ext_vector_type(4)));
typedef _Float16 h8v __attribute__((ext_vector_type(8)));
typedef float f32x4 __attribute__((ext_vector_type(4)));

// Weight-pack offsets (in halves) inside the contiguous wpk buffer.
#define O_W0L 0
#define O_W0S 65536
#define O_W0H 327680
#define O_W1L 589824
#define O_W1S 622592
#define O_W1H 655360
#define WPK_HALVES 688128
// X-pack offsets (halves) inside xpk: ori hi/lo then sm hi/lo.
#define XO_ORI 0
#define XO_SM  1572864          // 2 * 128 * 6144
#define XPK_HALVES 7864320      // + 2 * 512 * 6144
#define NMAXBLK (48 * 49 / 2)   // active blocks in max6 triangle

// ---------------------------------------------------------------------------
// Pack weights (ids 0-5) and X matrices (id 6 = ori, id 7 = sm) to fp16
// hi/lo in MFMA fragment k-major layout. Zeroes mx / completion counters.
// ---------------------------------------------------------------------------
__global__ __launch_bounds__(256) void pack_all_kernel(
    const float* __restrict__ W0l, const float* __restrict__ W0s_,
    const float* __restrict__ W0h, const float* __restrict__ W1l,
    const float* __restrict__ W1s_, const float* __restrict__ W1h,
    const float* __restrict__ ori, const float* __restrict__ sm,
    _Float16* __restrict__ pk, _Float16* __restrict__ xpk,
    unsigned int* __restrict__ mx, unsigned int* __restrict__ cntM,
    unsigned int* __restrict__ cntP)
{
    const int t = threadIdx.x;
    if (blockIdx.x == 0 && blockIdx.y == 0) {
        if (t == 0) { mx[0] = 0u; cntM[0] = 0u; }
        if (t < 192) cntP[t] = 0u;
    }
    const int id = blockIdx.y;
    const int idx = blockIdx.x * 256 + t;
    if (id < 6) {
        const float* src; int K, N, offhi;
        switch (id) {
            case 0:  src = W0l;  K = 128; N = 256; offhi = O_W0L; break;
            case 1:  src = W0s_; K = 512; N = 256; offhi = O_W0S; break;
            case 2:  src = W0h;  K = 512; N = 256; offhi = O_W0H; break;
            case 3:  src = W1l;  K = 256; N = 64;  offhi = O_W1L; break;
            case 4:  src = W1s_; K = 256; N = 64;  offhi = O_W1S; break;
            default: src = W1h;  K = 256; N = 64;  offhi = O_W1H; break;
        }
        const int cnt = (K * N) >> 3;
        if (idx >= cnt) return;
        const int col  = (N == 256) ? (idx & 255) : (idx & 63);
        const int kblk = (N == 256) ? (idx >> 8) : (idx >> 6);
        h8v hi, lo;
        #pragma unroll
        for (int e = 0; e < 8; ++e) {
            float x = src[(size_t)(kblk * 8 + e) * N + col];
            _Float16 h = (_Float16)x;
            hi[e] = h;
            lo[e] = (_Float16)(x - (float)h);
        }
        *reinterpret_cast<h8v*>(&pk[(size_t)offhi + (size_t)idx * 8]) = hi;
        *reinterpret_cast<h8v*>(&pk[(size_t)offhi + (size_t)(K * N) + (size_t)idx * 8]) = lo;
    } else {
        const float* Xs = (id == 6) ? ori : sm;
        const int K = (id == 6) ? FEATN : INSM;
        const int cnt = NN * (K >> 3);
        if (idx >= cnt) return;
        const int i = idx % NN, kblk = idx / NN;
        const float* p = &Xs[(size_t)i * K + kblk * 8];
        float4 a = *reinterpret_cast<const float4*>(p);
        float4 b = *reinterpret_cast<const float4*>(p + 4);
        float fv[8] = {a.x, a.y, a.z, a.w, b.x, b.y, b.z, b.w};
        h8v hi, lo;
        #pragma unroll
        for (int e = 0; e < 8; ++e) {
            _Float16 h = (_Float16)fv[e];
            hi[e] = h;
            lo[e] = (_Float16)(fv[e] - (float)h);
        }
        _Float16* xh = xpk + ((id == 6) ? XO_ORI : XO_SM);
        _Float16* xl = xh + (size_t)K * NN;
        *reinterpret_cast<h8v*>(&xh[(size_t)idx * 8]) = hi;   // idx = kblk*NN + i
        *reinterpret_cast<h8v*>(&xl[(size_t)idx * 8]) = lo;
    }
}

// ---------------------------------------------------------------------------
// MFMA MLP v3 (proven round 14): layer-1 fragments direct from xpk; br==2
// epilogue packs ehi/elo + uphi/uplo and writes f64 column partials.
// ---------------------------------------------------------------------------
__global__ __launch_bounds__(256) void mlp3_kernel(
    const _Float16* __restrict__ xpk, const _Float16* __restrict__ pk,
    const float* __restrict__ b0l, const float* __restrict__ b0s,
    const float* __restrict__ b0h, const float* __restrict__ b1l,
    const float* __restrict__ b1s, const float* __restrict__ b1h,
    const float* __restrict__ am_p, const float* __restrict__ ah_p,
    float* __restrict__ out, float* __restrict__ emb,
    _Float16* __restrict__ ehi, _Float16* __restrict__ elo,
    _Float16* __restrict__ uphi, _Float16* __restrict__ uplo,
    double* __restrict__ colpart)
{
    __shared__ __align__(16) char smem[32 * 264 * 4];   // 33792 B
    float* hs    = (float*)smem;            // [32][264] (layer2)
    float* vals  = (float*)smem;            // [32][65] logits (br2)
    float* uvals = (float*)(smem + 16384);  // [32][65] u rows (br2)
    double* cred = (double*)(smem + 24704); // [4][64] colsum partials (br2)

    const int t = threadIdx.x;
    const int br = blockIdx.y;
    const int r0 = blockIdx.x * 32;
    const int w = t >> 6, lane = t & 63, arow = lane & 15, ag = lane >> 4;

    const _Float16 *Ahi, *Alo, *B0hi, *B0lo, *B1hi, *B1lo;
    const float *bias0, *bias1;
    int K1; float alpha;
    if (br == 0) {
        Ahi = xpk + XO_ORI; Alo = Ahi + 128 * NN;
        B0hi = pk + O_W0L; B0lo = B0hi + 128 * 256;
        B1hi = pk + O_W1L; B1lo = B1hi + 256 * 64;
        bias0 = b0l; bias1 = b1l; K1 = FEATN; alpha = am_p[0];
    } else if (br == 1) {
        Ahi = xpk + XO_SM; Alo = Ahi + 512 * NN;
        B0hi = pk + O_W0S; B0lo = B0hi + 512 * 256;
        B1hi = pk + O_W1S; B1lo = B1hi + 256 * 64;
        bias0 = b0s; bias1 = b1s; K1 = INSM; alpha = am_p[0];
    } else {
        Ahi = xpk + XO_SM; Alo = Ahi + 512 * NN;
        B0hi = pk + O_W0H; B0lo = B0hi + 512 * 256;
        B1hi = pk + O_W1H; B1lo = B1hi + 256 * 64;
        bias0 = b0h; bias1 = b1h; K1 = INSM; alpha = ah_p[0];
    }
    const int nks = K1 >> 5;

    // ---- layer 1 ----
    f32x4 acc1[2][4] = {};
    for (int ks = 0; ks < nks; ++ks) {
        h8v ahi[2], alo8[2];
        #pragma unroll
        for (int rt = 0; rt < 2; ++rt) {
            const size_t ao = ((size_t)(ks * 4 + ag) * NN + r0 + rt * 16 + arow) * 8;
            ahi[rt]  = *reinterpret_cast<const h8v*>(&Ahi[ao]);
            alo8[rt] = *reinterpret_cast<const h8v*>(&Alo[ao]);
        }
        #pragma unroll
        for (int ct = 0; ct < 4; ++ct) {
            const size_t bidx =
                ((size_t)(ks * 4 + ag) * 256 + w * 64 + ct * 16 + arow) * 8;
            h8v bhi = *reinterpret_cast<const h8v*>(&B0hi[bidx]);
            h8v blo = *reinterpret_cast<const h8v*>(&B0lo[bidx]);
            #pragma unroll
            for (int rt = 0; rt < 2; ++rt) {
                acc1[rt][ct] = __builtin_amdgcn_mfma_f32_16x16x32_f16(ahi[rt], bhi, acc1[rt][ct], 0, 0, 0);
                acc1[rt][ct] = __builtin_amdgcn_mfma_f32_16x16x32_f16(ahi[rt], blo, acc1[rt][ct], 0, 0, 0);
                acc1[rt][ct] = __builtin_amdgcn_mfma_f32_16x16x32_f16(alo8[rt], bhi, acc1[rt][ct], 0, 0, 0);
            }
        }
    }

    #pragma unroll
    for (int ct = 0; ct < 4; ++ct) {
        const int col = w * 64 + ct * 16 + arow;
        const float bb = bias0[col];
        #pragma unroll
        for (int rt = 0; rt < 2; ++rt)
            #pragma unroll
            for (int r = 0; r < 4; ++r) {
                float h = acc1[rt][ct][r] + bb;
                hs[(rt * 16 + ag * 4 + r) * 264 + col] = (h >= 0.f) ? h : alpha * h;
            }
    }
    __syncthreads();

    // ---- layer 2 ----
    f32x4 acc2[2] = {};
    #pragma unroll
    for (int ks2 = 0; ks2 < 8; ++ks2) {
        const size_t bidx = ((size_t)(ks2 * 4 + ag) * 64 + w * 16 + arow) * 8;
        h8v bhi = *reinterpret_cast<const h8v*>(&B1hi[bidx]);
        h8v blo = *reinterpret_cast<const h8v*>(&B1lo[bidx]);
        #pragma unroll
        for (int rt = 0; rt < 2; ++rt) {
            const float* ap = &hs[(rt * 16 + arow) * 264 + ks2 * 32 + ag * 8];
            float4 a = *reinterpret_cast<const float4*>(ap);
            float4 b = *reinterpret_cast<const float4*>(ap + 4);
            float fv[8] = {a.x, a.y, a.z, a.w, b.x, b.y, b.z, b.w};
            h8v ahi8, alo8;
            #pragma unroll
            for (int e = 0; e < 8; ++e) {
                _Float16 h = (_Float16)fv[e];
                ahi8[e] = h;
                alo8[e] = (_Float16)(fv[e] - (float)h);
            }
            acc2[rt] = __builtin_amdgcn_mfma_f32_16x16x32_f16(ahi8, bhi, acc2[rt], 0, 0, 0);
            acc2[rt] = __builtin_amdgcn_mfma_f32_16x16x32_f16(ahi8, blo, acc2[rt], 0, 0, 0);
            acc2[rt] = __builtin_amdgcn_mfma_f32_16x16x32_f16(alo8, bhi, acc2[rt], 0, 0, 0);
        }
    }

    const int col2 = w * 16 + arow;
    const float bb1 = bias1[col2];
    if (br < 2) {
        float* dst = out + (size_t)br * NN * DOUT;
        #pragma unroll
        for (int rt = 0; rt < 2; ++rt)
            #pragma unroll
            for (int r = 0; r < 4; ++r)
                dst[(size_t)(r0 + rt * 16 + ag * 4 + r) * 64 + col2] =
                    acc2[rt][r] + bb1;
    } else {
        __syncthreads();                        // hs reads done; vals aliases
        #pragma unroll
        for (int rt = 0; rt < 2; ++rt)
            #pragma unroll
            for (int r = 0; r < 4; ++r)
                vals[(rt * 16 + ag * 4 + r) * 65 + col2] = acc2[rt][r] + bb1;
        __syncthreads();
        double myc = 0.0;
        for (int rr = 0; rr < 8; ++rr) {
            const int row = w * 8 + rr;
            float v = vals[row * 65 + lane];
            float mv = v;
            for (int off = 32; off > 0; off >>= 1) mv = fmaxf(mv, __shfl_xor(mv, off));
            float e = expf(v - mv);
            float ssum = e;
            for (int off = 32; off > 0; off >>= 1) ssum += __shfl_xor(ssum, off);
            float s = e / ssum;
            float n2 = s * s;
            for (int off = 32; off > 0; off >>= 1) n2 += __shfl_xor(n2, off);
            float uu = s * rsqrtf(n2);    // d_i >= 1/64 so max(.,1e-9) never binds
            emb[(size_t)(r0 + row) * 64 + lane] = v;
            uvals[row * 65 + lane] = uu;
            myc += (double)uu;
        }
        cred[w * 64 + lane] = myc;
        __syncthreads();                        // uvals + cred ready; vals intact
        {   // pack ehi/elo from vals
            const int jb = t >> 6, c = t & 63;
            h8v hi, lo;
            #pragma unroll
            for (int e = 0; e < 8; ++e) {
                float x = vals[(jb * 8 + e) * 65 + c];
                _Float16 h = (_Float16)x;
                hi[e] = h;
                lo[e] = (_Float16)(x - (float)h);
            }
            const size_t o = ((size_t)(r0 / 8 + jb) * 64 + c) * 8;
            *reinterpret_cast<h8v*>(&ehi[o]) = hi;
            *reinterpret_cast<h8v*>(&elo[o]) = lo;
        }
        {   // pack uphi/uplo from uvals
            const int kb = t >> 5, i = t & 31;
            h8v hi, lo;
            #pragma unroll
            for (int e = 0; e < 8; ++e) {
                float x = uvals[i * 65 + kb * 8 + e];
                _Float16 h = (_Float16)x;
                hi[e] = h;
                lo[e] = (_Float16)(x - (float)h);
            }
            const size_t o = ((size_t)kb * NN + r0 + i) * 8;
            *reinterpret_cast<h8v*>(&uphi[o]) = hi;
            *reinterpret_cast<h8v*>(&uplo[o]) = lo;
        }
        if (t < 64) {   // per-block column partial (fixed order -> deterministic)
            double cs = cred[t] + cred[64 + t] + cred[128 + t] + cred[192 + t];
            colpart[(size_t)blockIdx.x * 64 + t] = cs;
        }
    }
}

// ---------------------------------------------------------------------------
// MFMA max pass, 128x128 tiles (grid 48x48 triangle): wave owns 32 cols x
// 128 rows (acc[8][2]); unique A/B read once -> ~190 MB L2 (was 298 MB).
// Last finishing block (completion counter) runs the finalize math.
// ---------------------------------------------------------------------------
__global__ __launch_bounds__(256) void max6_kernel(
    const _Float16* __restrict__ uphi, const _Float16* __restrict__ uplo,
    const double* __restrict__ colpart, unsigned int* __restrict__ mx,
    unsigned int* __restrict__ cntM, float* __restrict__ scal)
{
    const int ti = blockIdx.x, tj = blockIdx.y;
    if (tj < ti) return;
    __shared__ float red[4];
    __shared__ unsigned int lastv;
    const int t = threadIdx.x;
    const int w = t >> 6, l = t & 63, arow = l & 15, ag = l >> 4;

    f32x4 acc[8][2] = {};                     // [rowfrag][colfrag]
    #pragma unroll
    for (int ks = 0; ks < 2; ++ks) {
        h8v bhi[2], blo[2];
        #pragma unroll
        for (int cf = 0; cf < 2; ++cf) {
            const size_t bo =
                ((size_t)(ks * 4 + ag) * NN + tj * 128 + w * 32 + cf * 16 + arow) * 8;
            bhi[cf] = *reinterpret_cast<const h8v*>(&uphi[bo]);
            blo[cf] = *reinterpret_cast<const h8v*>(&uplo[bo]);
        }
        #pragma unroll
        for (int rt = 0; rt < 8; ++rt) {
            const size_t ao =
                ((size_t)(ks * 4 + ag) * NN + ti * 128 + rt * 16 + arow) * 8;
            h8v ahi_ = *reinterpret_cast<const h8v*>(&uphi[ao]);
            h8v alo_ = *reinterpret_cast<const h8v*>(&uplo[ao]);
            #pragma unroll
            for (int cf = 0; cf < 2; ++cf) {
                acc[rt][cf] = __builtin_amdgcn_mfma_f32_16x16x32_f16(ahi_, bhi[cf], acc[rt][cf], 0, 0, 0);
                acc[rt][cf] = __builtin_amdgcn_mfma_f32_16x16x32_f16(ahi_, blo[cf], acc[rt][cf], 0, 0, 0);
                acc[rt][cf] = __builtin_amdgcn_mfma_f32_16x16x32_f16(alo_, bhi[cf], acc[rt][cf], 0, 0, 0);
            }
        }
    }
    float lm = 0.f;
    #pragma unroll
    for (int rt = 0; rt < 8; ++rt)
        #pragma unroll
        for (int cf = 0; cf < 2; ++cf) {
            const int gj = tj * 128 + w * 32 + cf * 16 + arow;
            #pragma unroll
            for (int r = 0; r < 4; ++r) {
                const int gi = ti * 128 + rt * 16 + ag * 4 + r;
                if (gi != gj) lm = fmaxf(lm, acc[rt][cf][r]);
            }
        }
    for (int off = 32; off > 0; off >>= 1) lm = fmaxf(lm, __shfl_xor(lm, off));
    if ((t & 63) == 0) red[t >> 6] = lm;
    __syncthreads();
    if (t == 0) {
        float bm = fmaxf(fmaxf(red[0], red[1]), fmaxf(red[2], red[3]));
        atomicMax(mx, __float_as_uint(bm));   // all candidates > 0
    }
    // ---- completion: last block runs finalize ----
    __threadfence();
    __syncthreads();
    if (t == 0) lastv = atomicAdd(cntM, 1u);
    __syncthreads();
    if (lastv == NMAXBLK - 1) {
        __threadfence();
        if (t < 64) {
            double cs = 0.0;
            for (int b = 0; b < 192; ++b) cs += colpart[(size_t)b * 64 + t];
            double s2 = cs * cs;
            for (int off = 32; off > 0; off >>= 1) s2 += __shfl_xor(s2, off);
            if (t == 0) {
                double md = (s2 - (double)NN) / ((double)NN * (double)NN);
                float mf = (float)md;
                float mxv = __uint_as_float(mx[0]);
                scal[0] = mf;
                scal[1] = 1.0f / (mxv - mf);
                scal[2] = 1.0f / mf;
            }
        }
    }
}

// ---------------------------------------------------------------------------
// Fused propagation v6 (proven round 13) + fused combine: the 8th (last)
// q-block per bi re-reads all partials in fixed order and runs the dual
// softmax epilogue (deterministic; counters zeroed by pack_all each call).
// ---------------------------------------------------------------------------
__global__ __launch_bounds__(256, 4) void prop6_kernel(
    const _Float16* __restrict__ uphi, const _Float16* __restrict__ uplo,
    const _Float16* __restrict__ ehi, const _Float16* __restrict__ elo,
    const float* __restrict__ emb,
    const float* __restrict__ scal, const float* __restrict__ ah_p,
    float* __restrict__ part, unsigned int* __restrict__ cntP,
    float* __restrict__ out3)
{
    __shared__ __align__(16) _Float16 Abuf[2][2][32 * 128];  // 32 KB
    __shared__ unsigned int lastq;

    const int t = threadIdx.x;
    const int bi = blockIdx.x;
    const int q = blockIdx.y;
    const int gi0 = bi * 32;
    const float m = scal[0], inv_pd = scal[1], inv_m = scal[2];
    const float alpha = ah_p[0];

    const int w = t >> 6, l = t & 63, arow = l & 15, ag = l >> 4;
    const int col = w * 16 + arow;

    h8v ubhi[2][2], ublo[2][2];              // [ks][ih]
    #pragma unroll
    for (int ks = 0; ks < 2; ++ks)
        #pragma unroll
        for (int ih = 0; ih < 2; ++ih) {
            const size_t o = ((size_t)(ks * 4 + ag) * NN + gi0 + ih * 16 + arow) * 8;
            ubhi[ks][ih] = *reinterpret_cast<const h8v*>(&uphi[o]);
            ublo[ks][ih] = *reinterpret_cast<const h8v*>(&uplo[o]);
        }

    f32x4 accP[2] = {};
    f32x4 accL[2] = {};

    const int jt0 = q * 6, jt1 = jt0 + 6;
    for (int jt = jt0; jt < jt1; ++jt) {
        const int buf = jt & 1;
        char* base = (char*)&Abuf[buf][0][0];
        #pragma unroll
        for (int ff = 0; ff < 2; ++ff) {
            const int f = w * 2 + ff;
            const int j0 = jt * 128 + f * 16;
            h8v jh0, jl0, jh1, jl1;
            {
                const size_t o0 = ((size_t)ag * NN + j0 + arow) * 8;
                jh0 = *reinterpret_cast<const h8v*>(&uphi[o0]);
                jl0 = *reinterpret_cast<const h8v*>(&uplo[o0]);
                const size_t o1 = ((size_t)(4 + ag) * NN + j0 + arow) * 8;
                jh1 = *reinterpret_cast<const h8v*>(&uphi[o1]);
                jl1 = *reinterpret_cast<const h8v*>(&uplo[o1]);
            }
            #pragma unroll
            for (int ih = 0; ih < 2; ++ih) {
                f32x4 aR0 = {0.f, 0.f, 0.f, 0.f};
                f32x4 aR1 = {0.f, 0.f, 0.f, 0.f};
                aR0 = __builtin_amdgcn_mfma_f32_16x16x32_f16(jh0, ubhi[0][ih], aR0, 0, 0, 0);
                aR0 = __builtin_amdgcn_mfma_f32_16x16x32_f16(jh0, ublo[0][ih], aR0, 0, 0, 0);
                aR0 = __builtin_amdgcn_mfma_f32_16x16x32_f16(jl0, ubhi[0][ih], aR0, 0, 0, 0);
                aR1 = __builtin_amdgcn_mfma_f32_16x16x32_f16(jh1, ubhi[1][ih], aR1, 0, 0, 0);
                aR1 = __builtin_amdgcn_mfma_f32_16x16x32_f16(jh1, ublo[1][ih], aR1, 0, 0, 0);
                aR1 = __builtin_amdgcn_mfma_f32_16x16x32_f16(jl1, ubhi[1][ih], aR1, 0, 0, 0);
                const int gi = gi0 + ih * 16 + arow;
                h4v vh4, ph4;
                #pragma unroll
                for (int r = 0; r < 4; ++r) {
                    const int gj = j0 + ag * 4 + r;
                    float rv = aR0[r] + aR1[r];
                    float lre = (gi == gj) ? 0.f : rv;
                    float x = lre - m;
                    float v = (x > 0.f) ? x * inv_pd : -(lre * inv_m);
                    if (gi == gj) v += 1.f;          // add_diag after where
                    float p = (v >= 0.f) ? v : alpha * v;
                    vh4[r] = (_Float16)v;
                    ph4[r] = (_Float16)p;
                }
                const int gl = f * 2 + (ag >> 1);
                const int byte = (ih * 16 + arow) * 256 +
                                 ((gl ^ (arow & 15)) << 4) + ((ag & 1) << 3);
                *reinterpret_cast<h4v*>(base + byte) = vh4;
                *reinterpret_cast<h4v*>(base + 8192 + byte) = ph4;
            }
        }
        __syncthreads();        // single barrier per tile (dbuf-safe)

        const char* cbase = (const char*)&Abuf[buf][0][0];
        __builtin_amdgcn_s_setprio(1);
        #pragma unroll
        for (int ks = 0; ks < 4; ++ks) {
            const size_t bidx = ((size_t)(jt * 16 + ks * 4 + ag) * 64 + col) * 8;
            h8v Bhi = *reinterpret_cast<const h8v*>(&ehi[bidx]);
            h8v Blo = *reinterpret_cast<const h8v*>(&elo[bidx]);
            #pragma unroll
            for (int ih = 0; ih < 2; ++ih) {
                const int abyte = (ih * 16 + arow) * 256 +
                                  (((ks * 4 + ag) ^ (arow & 15)) << 4);
                h8v vhiF = *reinterpret_cast<const h8v*>(cbase + abyte);
                h8v phiF = *reinterpret_cast<const h8v*>(cbase + 8192 + abyte);
                accP[ih] = __builtin_amdgcn_mfma_f32_16x16x32_f16(phiF, Bhi, accP[ih], 0, 0, 0);
                accP[ih] = __builtin_amdgcn_mfma_f32_16x16x32_f16(phiF, Blo, accP[ih], 0, 0, 0);
                accL[ih] = __builtin_amdgcn_mfma_f32_16x16x32_f16(vhiF, Bhi, accL[ih], 0, 0, 0);
                accL[ih] = __builtin_amdgcn_mfma_f32_16x16x32_f16(vhiF, Blo, accL[ih], 0, 0, 0);
            }
        }
        __builtin_amdgcn_s_setprio(0);
    }

    // ---- write P/L partials for this quarter ----
    {
        float* pbase = &part[((size_t)q * NN + gi0) * 128];
        #pragma unroll
        for (int ih = 0; ih < 2; ++ih)
            #pragma unroll
            for (int r = 0; r < 4; ++r) {
                const int row = ih * 16 + ag * 4 + r;
                pbase[(size_t)row * 128 + col] = accP[ih][r];
                pbase[(size_t)row * 128 + 64 + col] = accL[ih][r];
            }
    }

    // ---- completion: last q-block for this bi runs the combine ----
    __threadfence();
    __syncthreads();
    if (t == 0) lastq = atomicAdd(&cntP[bi], 1u);
    __syncthreads();
    if (lastq == 7) {
        __threadfence();
        const float one_pa = 1.f + alpha;
        for (int rr = 0; rr < 8; ++rr) {
            const int row = w * 8 + rr;              // 4 waves x 8 rows = 32
            const int gi = gi0 + row;
            float zp = 0.f, zl = 0.f;
            #pragma unroll
            for (int q2 = 0; q2 < 8; ++q2) {
                const float* p = &part[((size_t)q2 * NN + gi) * 128];
                zp += p[l];
                zl += p[64 + l];
            }
            float zn = zp - one_pa * zl;

            float mp = zp;
            for (int off = 32; off > 0; off >>= 1) mp = fmaxf(mp, __shfl_xor(mp, off));
            float ep = __expf(zp - mp);
            float sump = ep;
            for (int off = 32; off > 0; off >>= 1) sump += __shfl_xor(sump, off);
            float pp = ep / sump;

            float mn = zn;
            for (int off = 32; off > 0; off >>= 1) mn = fmaxf(mn, __shfl_xor(mn, off));
            float en = __expf(zn - mn);
            float sumn = en;
            for (int off = 32; off > 0; off >>= 1) sumn += __shfl_xor(sumn, off);
            float pn = en / sumn;

            out3[(size_t)gi * 64 + l] = 0.5f * (pp - pn + emb[(size_t)gi * 64 + l]);
        }
    }
}

extern "C" void kernel_launch(void* const* d_in, const int* in_sizes, int n_in,
                              void* d_out, int out_size, void* d_ws, size_t ws_size,
                              hipStream_t stream)
{
    (void)in_sizes; (void)n_in; (void)out_size; (void)ws_size;
    const float* ori = (const float*)d_in[0];
    const float* sm  = (const float*)d_in[1];
    // d_in[2] processed_feature: unused; d_in[3] universal_re: unused (BETA=0)
    const float* W0s = (const float*)d_in[4];
    const float* b0s = (const float*)d_in[5];
    const float* W1s = (const float*)d_in[6];
    const float* b1s = (const float*)d_in[7];
    const float* W0l = (const float*)d_in[8];
    const float* b0l = (const float*)d_in[9];
    const float* W1l = (const float*)d_in[10];
    const float* b1l = (const float*)d_in[11];
    const float* W0h = (const float*)d_in[12];
    const float* b0h = (const float*)d_in[13];
    const float* W1h = (const float*)d_in[14];
    const float* b1h = (const float*)d_in[15];
    const float* amp = (const float*)d_in[16];
    const float* ahp = (const float*)d_in[17];

    float* out = (float*)d_out;                       // f32 output (ref dtype)
    float* ws = (float*)d_ws;
    float* emb = ws;                                            // 393216 f32
    double* colpart = (double*)(ws + (size_t)NN * DOUT);        // 192*64 f64
    unsigned int* mx = (unsigned int*)(ws + (size_t)NN * DOUT + 24576);
    float* scal = ws + (size_t)NN * DOUT + 24576 + 4;           // 3 f32
    unsigned int* cntM = (unsigned int*)(ws + (size_t)NN * DOUT + 24576 + 8);
    unsigned int* cntP = cntM + 1;                              // 192 ints
    size_t eh_off = (size_t)NN * DOUT + 24576 + 256;            // 16B-aligned
    _Float16* ehi = (_Float16*)(ws + eh_off);                   // NN*64 halves
    _Float16* elo = ehi + (size_t)NN * DOUT;
    size_t up_off = eh_off + (size_t)NN * DOUT;                 // f32 words
    _Float16* uphi = (_Float16*)(ws + up_off);
    _Float16* uplo = uphi + (size_t)NN * DOUT;
    size_t wpk_off = up_off + (size_t)NN * DOUT;
    _Float16* wpk = (_Float16*)(ws + wpk_off);                  // 688128 halves
    size_t sh_off = (wpk_off + WPK_HALVES / 2 + 3) & ~(size_t)3;
    _Float16* xpk = (_Float16*)(ws + sh_off);   // 7864320 halves (mlp phase)
    float* part = ws + sh_off;                  // 8*NN*128 f32 (prop phase)
    // xpk and part alias: xpk dead after mlp3; part born in prop6.
    // total ws footprint ~31.4 MB

    pack_all_kernel<<<dim3(1536, 8), 256, 0, stream>>>(
        W0l, W0s, W0h, W1l, W1s, W1h, ori, sm, wpk, xpk, mx, cntM, cntP);
    mlp3_kernel<<<dim3(NN / 32, 3), 256, 0, stream>>>(
        xpk, wpk, b0l, b0s, b0h, b1l, b1s, b1h, amp, ahp,
        out, emb, ehi, elo, uphi, uplo, colpart);
    max6_kernel<<<dim3(48, 48), 256, 0, stream>>>(
        uphi, uplo, colpart, mx, cntM, scal);
    prop6_kernel<<<dim3(NN / 32, 8), 256, 0, stream>>>(
        uphi, uplo, ehi, elo, emb, scal, ahp, part, cntP,
        out + (size_t)2 * NN * DOUT);
}

// Round 16
// 119.686 us; speedup vs baseline: 3.3329x; 3.3329x over previous
//
#include <hip/hip_runtime.h>
#include <hip/hip_bf16.h>

#define NN 6144
#define FEATN 128
#define INSM 512
#define HIDN 256
#define DOUT 64

typedef _Float16 h4v __attribute__((ext_vector_type(4)));
typedef _Float16 h8v __attribute__((ext_vector_type(8)));
typedef float f32x4 __attribute__((ext_vector_type(4)));

// Weight-pack offsets (in halves) inside the contiguous wpk buffer.
#define O_W0L 0
#define O_W0S 65536
#define O_W0H 327680
#define O_W1L 589824
#define O_W1S 622592
#define O_W1H 655360
#define WPK_HALVES 688128
// X-pack offsets (halves) inside xpk: ori hi/lo then sm hi/lo.
#define XO_ORI 0
#define XO_SM  1572864          // 2 * 128 * 6144
#define XPK_HALVES 7864320      // + 2 * 512 * 6144

// ---------------------------------------------------------------------------
// Pack weights (ids 0-5) and X matrices (id 6 = ori, id 7 = sm) to fp16
// hi/lo in MFMA fragment k-major layout. Zeroes mx (block 0).
// ---------------------------------------------------------------------------
__global__ __launch_bounds__(256) void pack_all_kernel(
    const float* __restrict__ W0l, const float* __restrict__ W0s_,
    const float* __restrict__ W0h, const float* __restrict__ W1l,
    const float* __restrict__ W1s_, const float* __restrict__ W1h,
    const float* __restrict__ ori, const float* __restrict__ sm,
    _Float16* __restrict__ pk, _Float16* __restrict__ xpk,
    unsigned int* __restrict__ mx)
{
    const int t = threadIdx.x;
    if (blockIdx.x == 0 && blockIdx.y == 0 && t == 0) mx[0] = 0u;
    const int id = blockIdx.y;
    const int idx = blockIdx.x * 256 + t;
    if (id < 6) {
        const float* src; int K, N, offhi;
        switch (id) {
            case 0:  src = W0l;  K = 128; N = 256; offhi = O_W0L; break;
            case 1:  src = W0s_; K = 512; N = 256; offhi = O_W0S; break;
            case 2:  src = W0h;  K = 512; N = 256; offhi = O_W0H; break;
            case 3:  src = W1l;  K = 256; N = 64;  offhi = O_W1L; break;
            case 4:  src = W1s_; K = 256; N = 64;  offhi = O_W1S; break;
            default: src = W1h;  K = 256; N = 64;  offhi = O_W1H; break;
        }
        const int cnt = (K * N) >> 3;
        if (idx >= cnt) return;
        const int col  = (N == 256) ? (idx & 255) : (idx & 63);
        const int kblk = (N == 256) ? (idx >> 8) : (idx >> 6);
        h8v hi, lo;
        #pragma unroll
        for (int e = 0; e < 8; ++e) {
            float x = src[(size_t)(kblk * 8 + e) * N + col];
            _Float16 h = (_Float16)x;
            hi[e] = h;
            lo[e] = (_Float16)(x - (float)h);
        }
        *reinterpret_cast<h8v*>(&pk[(size_t)offhi + (size_t)idx * 8]) = hi;
        *reinterpret_cast<h8v*>(&pk[(size_t)offhi + (size_t)(K * N) + (size_t)idx * 8]) = lo;
    } else {
        const float* Xs = (id == 6) ? ori : sm;
        const int K = (id == 6) ? FEATN : INSM;
        const int cnt = NN * (K >> 3);
        if (idx >= cnt) return;
        const int i = idx % NN, kblk = idx / NN;
        const float* p = &Xs[(size_t)i * K + kblk * 8];
        float4 a = *reinterpret_cast<const float4*>(p);
        float4 b = *reinterpret_cast<const float4*>(p + 4);
        float fv[8] = {a.x, a.y, a.z, a.w, b.x, b.y, b.z, b.w};
        h8v hi, lo;
        #pragma unroll
        for (int e = 0; e < 8; ++e) {
            _Float16 h = (_Float16)fv[e];
            hi[e] = h;
            lo[e] = (_Float16)(fv[e] - (float)h);
        }
        _Float16* xh = xpk + ((id == 6) ? XO_ORI : XO_SM);
        _Float16* xl = xh + (size_t)K * NN;
        *reinterpret_cast<h8v*>(&xh[(size_t)idx * 8]) = hi;   // idx = kblk*NN + i
        *reinterpret_cast<h8v*>(&xl[(size_t)idx * 8]) = lo;
    }
}

// ---------------------------------------------------------------------------
// MFMA MLP v3 (proven round 14): layer-1 fragments direct from xpk; br==2
// epilogue packs ehi/elo + uphi/uplo and writes f64 column partials.
// ---------------------------------------------------------------------------
__global__ __launch_bounds__(256) void mlp3_kernel(
    const _Float16* __restrict__ xpk, const _Float16* __restrict__ pk,
    const float* __restrict__ b0l, const float* __restrict__ b0s,
    const float* __restrict__ b0h, const float* __restrict__ b1l,
    const float* __restrict__ b1s, const float* __restrict__ b1h,
    const float* __restrict__ am_p, const float* __restrict__ ah_p,
    float* __restrict__ out, float* __restrict__ emb,
    _Float16* __restrict__ ehi, _Float16* __restrict__ elo,
    _Float16* __restrict__ uphi, _Float16* __restrict__ uplo,
    double* __restrict__ colpart)
{
    __shared__ __align__(16) char smem[32 * 264 * 4];   // 33792 B
    float* hs    = (float*)smem;            // [32][264] (layer2)
    float* vals  = (float*)smem;            // [32][65] logits (br2)
    float* uvals = (float*)(smem + 16384);  // [32][65] u rows (br2)
    double* cred = (double*)(smem + 24704); // [4][64] colsum partials (br2)

    const int t = threadIdx.x;
    const int br = blockIdx.y;
    const int r0 = blockIdx.x * 32;
    const int w = t >> 6, lane = t & 63, arow = lane & 15, ag = lane >> 4;

    const _Float16 *Ahi, *Alo, *B0hi, *B0lo, *B1hi, *B1lo;
    const float *bias0, *bias1;
    int K1; float alpha;
    if (br == 0) {
        Ahi = xpk + XO_ORI; Alo = Ahi + 128 * NN;
        B0hi = pk + O_W0L; B0lo = B0hi + 128 * 256;
        B1hi = pk + O_W1L; B1lo = B1hi + 256 * 64;
        bias0 = b0l; bias1 = b1l; K1 = FEATN; alpha = am_p[0];
    } else if (br == 1) {
        Ahi = xpk + XO_SM; Alo = Ahi + 512 * NN;
        B0hi = pk + O_W0S; B0lo = B0hi + 512 * 256;
        B1hi = pk + O_W1S; B1lo = B1hi + 256 * 64;
        bias0 = b0s; bias1 = b1s; K1 = INSM; alpha = am_p[0];
    } else {
        Ahi = xpk + XO_SM; Alo = Ahi + 512 * NN;
        B0hi = pk + O_W0H; B0lo = B0hi + 512 * 256;
        B1hi = pk + O_W1H; B1lo = B1hi + 256 * 64;
        bias0 = b0h; bias1 = b1h; K1 = INSM; alpha = ah_p[0];
    }
    const int nks = K1 >> 5;

    // ---- layer 1 ----
    f32x4 acc1[2][4] = {};
    for (int ks = 0; ks < nks; ++ks) {
        h8v ahi[2], alo8[2];
        #pragma unroll
        for (int rt = 0; rt < 2; ++rt) {
            const size_t ao = ((size_t)(ks * 4 + ag) * NN + r0 + rt * 16 + arow) * 8;
            ahi[rt]  = *reinterpret_cast<const h8v*>(&Ahi[ao]);
            alo8[rt] = *reinterpret_cast<const h8v*>(&Alo[ao]);
        }
        #pragma unroll
        for (int ct = 0; ct < 4; ++ct) {
            const size_t bidx =
                ((size_t)(ks * 4 + ag) * 256 + w * 64 + ct * 16 + arow) * 8;
            h8v bhi = *reinterpret_cast<const h8v*>(&B0hi[bidx]);
            h8v blo = *reinterpret_cast<const h8v*>(&B0lo[bidx]);
            #pragma unroll
            for (int rt = 0; rt < 2; ++rt) {
                acc1[rt][ct] = __builtin_amdgcn_mfma_f32_16x16x32_f16(ahi[rt], bhi, acc1[rt][ct], 0, 0, 0);
                acc1[rt][ct] = __builtin_amdgcn_mfma_f32_16x16x32_f16(ahi[rt], blo, acc1[rt][ct], 0, 0, 0);
                acc1[rt][ct] = __builtin_amdgcn_mfma_f32_16x16x32_f16(alo8[rt], bhi, acc1[rt][ct], 0, 0, 0);
            }
        }
    }

    #pragma unroll
    for (int ct = 0; ct < 4; ++ct) {
        const int col = w * 64 + ct * 16 + arow;
        const float bb = bias0[col];
        #pragma unroll
        for (int rt = 0; rt < 2; ++rt)
            #pragma unroll
            for (int r = 0; r < 4; ++r) {
                float h = acc1[rt][ct][r] + bb;
                hs[(rt * 16 + ag * 4 + r) * 264 + col] = (h >= 0.f) ? h : alpha * h;
            }
    }
    __syncthreads();

    // ---- layer 2 ----
    f32x4 acc2[2] = {};
    #pragma unroll
    for (int ks2 = 0; ks2 < 8; ++ks2) {
        const size_t bidx = ((size_t)(ks2 * 4 + ag) * 64 + w * 16 + arow) * 8;
        h8v bhi = *reinterpret_cast<const h8v*>(&B1hi[bidx]);
        h8v blo = *reinterpret_cast<const h8v*>(&B1lo[bidx]);
        #pragma unroll
        for (int rt = 0; rt < 2; ++rt) {
            const float* ap = &hs[(rt * 16 + arow) * 264 + ks2 * 32 + ag * 8];
            float4 a = *reinterpret_cast<const float4*>(ap);
            float4 b = *reinterpret_cast<const float4*>(ap + 4);
            float fv[8] = {a.x, a.y, a.z, a.w, b.x, b.y, b.z, b.w};
            h8v ahi8, alo8;
            #pragma unroll
            for (int e = 0; e < 8; ++e) {
                _Float16 h = (_Float16)fv[e];
                ahi8[e] = h;
                alo8[e] = (_Float16)(fv[e] - (float)h);
            }
            acc2[rt] = __builtin_amdgcn_mfma_f32_16x16x32_f16(ahi8, bhi, acc2[rt], 0, 0, 0);
            acc2[rt] = __builtin_amdgcn_mfma_f32_16x16x32_f16(ahi8, blo, acc2[rt], 0, 0, 0);
            acc2[rt] = __builtin_amdgcn_mfma_f32_16x16x32_f16(alo8, bhi, acc2[rt], 0, 0, 0);
        }
    }

    const int col2 = w * 16 + arow;
    const float bb1 = bias1[col2];
    if (br < 2) {
        float* dst = out + (size_t)br * NN * DOUT;
        #pragma unroll
        for (int rt = 0; rt < 2; ++rt)
            #pragma unroll
            for (int r = 0; r < 4; ++r)
                dst[(size_t)(r0 + rt * 16 + ag * 4 + r) * 64 + col2] =
                    acc2[rt][r] + bb1;
    } else {
        __syncthreads();                        // hs reads done; vals aliases
        #pragma unroll
        for (int rt = 0; rt < 2; ++rt)
            #pragma unroll
            for (int r = 0; r < 4; ++r)
                vals[(rt * 16 + ag * 4 + r) * 65 + col2] = acc2[rt][r] + bb1;
        __syncthreads();
        double myc = 0.0;
        for (int rr = 0; rr < 8; ++rr) {
            const int row = w * 8 + rr;
            float v = vals[row * 65 + lane];
            float mv = v;
            for (int off = 32; off > 0; off >>= 1) mv = fmaxf(mv, __shfl_xor(mv, off));
            float e = expf(v - mv);
            float ssum = e;
            for (int off = 32; off > 0; off >>= 1) ssum += __shfl_xor(ssum, off);
            float s = e / ssum;
            float n2 = s * s;
            for (int off = 32; off > 0; off >>= 1) n2 += __shfl_xor(n2, off);
            float uu = s * rsqrtf(n2);    // d_i >= 1/64 so max(.,1e-9) never binds
            emb[(size_t)(r0 + row) * 64 + lane] = v;
            uvals[row * 65 + lane] = uu;
            myc += (double)uu;
        }
        cred[w * 64 + lane] = myc;
        __syncthreads();                        // uvals + cred ready; vals intact
        {   // pack ehi/elo from vals
            const int jb = t >> 6, c = t & 63;
            h8v hi, lo;
            #pragma unroll
            for (int e = 0; e < 8; ++e) {
                float x = vals[(jb * 8 + e) * 65 + c];
                _Float16 h = (_Float16)x;
                hi[e] = h;
                lo[e] = (_Float16)(x - (float)h);
            }
            const size_t o = ((size_t)(r0 / 8 + jb) * 64 + c) * 8;
            *reinterpret_cast<h8v*>(&ehi[o]) = hi;
            *reinterpret_cast<h8v*>(&elo[o]) = lo;
        }
        {   // pack uphi/uplo from uvals
            const int kb = t >> 5, i = t & 31;
            h8v hi, lo;
            #pragma unroll
            for (int e = 0; e < 8; ++e) {
                float x = uvals[i * 65 + kb * 8 + e];
                _Float16 h = (_Float16)x;
                hi[e] = h;
                lo[e] = (_Float16)(x - (float)h);
            }
            const size_t o = ((size_t)kb * NN + r0 + i) * 8;
            *reinterpret_cast<h8v*>(&uphi[o]) = hi;
            *reinterpret_cast<h8v*>(&uplo[o]) = lo;
        }
        if (t < 64) {   // per-block column partial (fixed order -> deterministic)
            double cs = cred[t] + cred[64 + t] + cred[128 + t] + cred[192 + t];
            colpart[(size_t)blockIdx.x * 64 + t] = cs;
        }
    }
}

// ---------------------------------------------------------------------------
// MFMA max pass, 128x128 tiles (grid 48x48 triangle), NO fence/fusion:
// wave owns 32 cols x 128 rows (acc[8][2]); halves L2 traffic vs 64-tiles.
// ---------------------------------------------------------------------------
__global__ __launch_bounds__(256) void max6_kernel(
    const _Float16* __restrict__ uphi, const _Float16* __restrict__ uplo,
    unsigned int* __restrict__ mx)
{
    const int ti = blockIdx.x, tj = blockIdx.y;
    if (tj < ti) return;
    __shared__ float red[4];
    const int t = threadIdx.x;
    const int w = t >> 6, l = t & 63, arow = l & 15, ag = l >> 4;

    f32x4 acc[8][2] = {};                     // [rowfrag][colfrag]
    #pragma unroll
    for (int ks = 0; ks < 2; ++ks) {
        h8v bhi[2], blo[2];
        #pragma unroll
        for (int cf = 0; cf < 2; ++cf) {
            const size_t bo =
                ((size_t)(ks * 4 + ag) * NN + tj * 128 + w * 32 + cf * 16 + arow) * 8;
            bhi[cf] = *reinterpret_cast<const h8v*>(&uphi[bo]);
            blo[cf] = *reinterpret_cast<const h8v*>(&uplo[bo]);
        }
        #pragma unroll
        for (int rt = 0; rt < 8; ++rt) {
            const size_t ao =
                ((size_t)(ks * 4 + ag) * NN + ti * 128 + rt * 16 + arow) * 8;
            h8v ahi_ = *reinterpret_cast<const h8v*>(&uphi[ao]);
            h8v alo_ = *reinterpret_cast<const h8v*>(&uplo[ao]);
            #pragma unroll
            for (int cf = 0; cf < 2; ++cf) {
                acc[rt][cf] = __builtin_amdgcn_mfma_f32_16x16x32_f16(ahi_, bhi[cf], acc[rt][cf], 0, 0, 0);
                acc[rt][cf] = __builtin_amdgcn_mfma_f32_16x16x32_f16(ahi_, blo[cf], acc[rt][cf], 0, 0, 0);
                acc[rt][cf] = __builtin_amdgcn_mfma_f32_16x16x32_f16(alo_, bhi[cf], acc[rt][cf], 0, 0, 0);
            }
        }
    }
    float lm = 0.f;
    #pragma unroll
    for (int rt = 0; rt < 8; ++rt)
        #pragma unroll
        for (int cf = 0; cf < 2; ++cf) {
            const int gj = tj * 128 + w * 32 + cf * 16 + arow;
            #pragma unroll
            for (int r = 0; r < 4; ++r) {
                const int gi = ti * 128 + rt * 16 + ag * 4 + r;
                if (gi != gj) lm = fmaxf(lm, acc[rt][cf][r]);
            }
        }
    for (int off = 32; off > 0; off >>= 1) lm = fmaxf(lm, __shfl_xor(lm, off));
    if ((t & 63) == 0) red[t >> 6] = lm;
    __syncthreads();
    if (t == 0) {
        float bm = fmaxf(fmaxf(red[0], red[1]), fmaxf(red[2], red[3]));
        atomicMax(mx, __float_as_uint(bm));   // all candidates > 0
    }
}

__global__ void finalize_kernel(const double* __restrict__ colpart,
                                const unsigned int* __restrict__ mx,
                                float* __restrict__ scal)
{
    const int c = threadIdx.x;   // 64 threads = 1 wave
    double cs = 0.0;
    for (int b = 0; b < 192; ++b) cs += colpart[(size_t)b * 64 + c];
    double s2 = cs * cs;
    for (int off = 32; off > 0; off >>= 1) s2 += __shfl_xor(s2, off);
    if (c == 0) {
        double md = (s2 - (double)NN) / ((double)NN * (double)NN);
        float mf = (float)md;
        float mxv = __uint_as_float(mx[0]);
        scal[0] = mf;
        scal[1] = 1.0f / (mxv - mf);
        scal[2] = 1.0f / mf;
    }
}

// ---------------------------------------------------------------------------
// Fused propagation v6 (proven rounds 13/14): 32 i-rows/block, grid (192, 8).
// ---------------------------------------------------------------------------
__global__ __launch_bounds__(256, 4) void prop6_kernel(
    const _Float16* __restrict__ uphi, const _Float16* __restrict__ uplo,
    const _Float16* __restrict__ ehi, const _Float16* __restrict__ elo,
    const float* __restrict__ scal, const float* __restrict__ ah_p,
    float* __restrict__ part)
{
    __shared__ __align__(16) _Float16 Abuf[2][2][32 * 128];  // 32 KB

    const int t = threadIdx.x;
    const int bi = blockIdx.x;
    const int q = blockIdx.y;
    const int gi0 = bi * 32;
    const float m = scal[0], inv_pd = scal[1], inv_m = scal[2];
    const float alpha = ah_p[0];

    const int w = t >> 6, l = t & 63, arow = l & 15, ag = l >> 4;
    const int col = w * 16 + arow;

    h8v ubhi[2][2], ublo[2][2];              // [ks][ih]
    #pragma unroll
    for (int ks = 0; ks < 2; ++ks)
        #pragma unroll
        for (int ih = 0; ih < 2; ++ih) {
            const size_t o = ((size_t)(ks * 4 + ag) * NN + gi0 + ih * 16 + arow) * 8;
            ubhi[ks][ih] = *reinterpret_cast<const h8v*>(&uphi[o]);
            ublo[ks][ih] = *reinterpret_cast<const h8v*>(&uplo[o]);
        }

    f32x4 accP[2] = {};
    f32x4 accL[2] = {};

    const int jt0 = q * 6, jt1 = jt0 + 6;
    for (int jt = jt0; jt < jt1; ++jt) {
        const int buf = jt & 1;
        char* base = (char*)&Abuf[buf][0][0];
        #pragma unroll
        for (int ff = 0; ff < 2; ++ff) {
            const int f = w * 2 + ff;
            const int j0 = jt * 128 + f * 16;
            h8v jh0, jl0, jh1, jl1;
            {
                const size_t o0 = ((size_t)ag * NN + j0 + arow) * 8;
                jh0 = *reinterpret_cast<const h8v*>(&uphi[o0]);
                jl0 = *reinterpret_cast<const h8v*>(&uplo[o0]);
                const size_t o1 = ((size_t)(4 + ag) * NN + j0 + arow) * 8;
                jh1 = *reinterpret_cast<const h8v*>(&uphi[o1]);
                jl1 = *reinterpret_cast<const h8v*>(&uplo[o1]);
            }
            #pragma unroll
            for (int ih = 0; ih < 2; ++ih) {
                f32x4 aR0 = {0.f, 0.f, 0.f, 0.f};
                f32x4 aR1 = {0.f, 0.f, 0.f, 0.f};
                aR0 = __builtin_amdgcn_mfma_f32_16x16x32_f16(jh0, ubhi[0][ih], aR0, 0, 0, 0);
                aR0 = __builtin_amdgcn_mfma_f32_16x16x32_f16(jh0, ublo[0][ih], aR0, 0, 0, 0);
                aR0 = __builtin_amdgcn_mfma_f32_16x16x32_f16(jl0, ubhi[0][ih], aR0, 0, 0, 0);
                aR1 = __builtin_amdgcn_mfma_f32_16x16x32_f16(jh1, ubhi[1][ih], aR1, 0, 0, 0);
                aR1 = __builtin_amdgcn_mfma_f32_16x16x32_f16(jh1, ublo[1][ih], aR1, 0, 0, 0);
                aR1 = __builtin_amdgcn_mfma_f32_16x16x32_f16(jl1, ubhi[1][ih], aR1, 0, 0, 0);
                const int gi = gi0 + ih * 16 + arow;
                h4v vh4, ph4;
                #pragma unroll
                for (int r = 0; r < 4; ++r) {
                    const int gj = j0 + ag * 4 + r;
                    float rv = aR0[r] + aR1[r];
                    float lre = (gi == gj) ? 0.f : rv;
                    float x = lre - m;
                    float v = (x > 0.f) ? x * inv_pd : -(lre * inv_m);
                    if (gi == gj) v += 1.f;          // add_diag after where
                    float p = (v >= 0.f) ? v : alpha * v;
                    vh4[r] = (_Float16)v;
                    ph4[r] = (_Float16)p;
                }
                const int gl = f * 2 + (ag >> 1);
                const int byte = (ih * 16 + arow) * 256 +
                                 ((gl ^ (arow & 15)) << 4) + ((ag & 1) << 3);
                *reinterpret_cast<h4v*>(base + byte) = vh4;
                *reinterpret_cast<h4v*>(base + 8192 + byte) = ph4;
            }
        }
        __syncthreads();        // single barrier per tile (dbuf-safe)

        const char* cbase = (const char*)&Abuf[buf][0][0];
        __builtin_amdgcn_s_setprio(1);
        #pragma unroll
        for (int ks = 0; ks < 4; ++ks) {
            const size_t bidx = ((size_t)(jt * 16 + ks * 4 + ag) * 64 + col) * 8;
            h8v Bhi = *reinterpret_cast<const h8v*>(&ehi[bidx]);
            h8v Blo = *reinterpret_cast<const h8v*>(&elo[bidx]);
            #pragma unroll
            for (int ih = 0; ih < 2; ++ih) {
                const int abyte = (ih * 16 + arow) * 256 +
                                  (((ks * 4 + ag) ^ (arow & 15)) << 4);
                h8v vhiF = *reinterpret_cast<const h8v*>(cbase + abyte);
                h8v phiF = *reinterpret_cast<const h8v*>(cbase + 8192 + abyte);
                accP[ih] = __builtin_amdgcn_mfma_f32_16x16x32_f16(phiF, Bhi, accP[ih], 0, 0, 0);
                accP[ih] = __builtin_amdgcn_mfma_f32_16x16x32_f16(phiF, Blo, accP[ih], 0, 0, 0);
                accL[ih] = __builtin_amdgcn_mfma_f32_16x16x32_f16(vhiF, Bhi, accL[ih], 0, 0, 0);
                accL[ih] = __builtin_amdgcn_mfma_f32_16x16x32_f16(vhiF, Blo, accL[ih], 0, 0, 0);
            }
        }
        __builtin_amdgcn_s_setprio(0);
    }

    {
        float* pbase = &part[((size_t)q * NN + gi0) * 128];
        #pragma unroll
        for (int ih = 0; ih < 2; ++ih)
            #pragma unroll
            for (int r = 0; r < 4; ++r) {
                const int row = ih * 16 + ag * 4 + r;
                pbase[(size_t)row * 128 + col] = accP[ih][r];
                pbase[(size_t)row * 128 + 64 + col] = accL[ih][r];
            }
    }
}

// ---------------------------------------------------------------------------
// Combine 8 partials: P = sum, L = sum, N = P - (1+alpha)L, dual softmax,
// epilogue -> out3.
// ---------------------------------------------------------------------------
__global__ __launch_bounds__(256) void combine4_kernel(
    const float* __restrict__ part, const float* __restrict__ emb,
    const float* __restrict__ ah_p, float* __restrict__ out3)
{
    const int t = threadIdx.x;
    const int w = t >> 6, l = t & 63;
    const int gi0 = blockIdx.x * 16;
    const float one_pa = 1.f + ah_p[0];
    #pragma unroll
    for (int rr = 0; rr < 4; ++rr) {
        const int gi = gi0 + w * 4 + rr;
        float zp = 0.f, zl = 0.f;
        #pragma unroll
        for (int q = 0; q < 8; ++q) {
            const float* p = &part[((size_t)q * NN + gi) * 128];
            zp += p[l];
            zl += p[64 + l];
        }
        float zn = zp - one_pa * zl;

        float mp = zp;
        for (int off = 32; off > 0; off >>= 1) mp = fmaxf(mp, __shfl_xor(mp, off));
        float ep = __expf(zp - mp);
        float sump = ep;
        for (int off = 32; off > 0; off >>= 1) sump += __shfl_xor(sump, off);
        float pp = ep / sump;

        float mn = zn;
        for (int off = 32; off > 0; off >>= 1) mn = fmaxf(mn, __shfl_xor(mn, off));
        float en = __expf(zn - mn);
        float sumn = en;
        for (int off = 32; off > 0; off >>= 1) sumn += __shfl_xor(sumn, off);
        float pn = en / sumn;

        out3[(size_t)gi * 64 + l] = 0.5f * (pp - pn + emb[(size_t)gi * 64 + l]);
    }
}

extern "C" void kernel_launch(void* const* d_in, const int* in_sizes, int n_in,
                              void* d_out, int out_size, void* d_ws, size_t ws_size,
                              hipStream_t stream)
{
    (void)in_sizes; (void)n_in; (void)out_size; (void)ws_size;
    const float* ori = (const float*)d_in[0];
    const float* sm  = (const float*)d_in[1];
    // d_in[2] processed_feature: unused; d_in[3] universal_re: unused (BETA=0)
    const float* W0s = (const float*)d_in[4];
    const float* b0s = (const float*)d_in[5];
    const float* W1s = (const float*)d_in[6];
    const float* b1s = (const float*)d_in[7];
    const float* W0l = (const float*)d_in[8];
    const float* b0l = (const float*)d_in[9];
    const float* W1l = (const float*)d_in[10];
    const float* b1l = (const float*)d_in[11];
    const float* W0h = (const float*)d_in[12];
    const float* b0h = (const float*)d_in[13];
    const float* W1h = (const float*)d_in[14];
    const float* b1h = (const float*)d_in[15];
    const float* amp = (const float*)d_in[16];
    const float* ahp = (const float*)d_in[17];

    float* out = (float*)d_out;                       // f32 output (ref dtype)
    float* ws = (float*)d_ws;
    float* emb = ws;                                            // 393216 f32
    double* colpart = (double*)(ws + (size_t)NN * DOUT);        // 192*64 f64
    unsigned int* mx = (unsigned int*)(ws + (size_t)NN * DOUT + 24576);
    float* scal = ws + (size_t)NN * DOUT + 24576 + 4;           // 3 f32
    size_t eh_off = (size_t)NN * DOUT + 24576 + 8;              // 16B-aligned
    _Float16* ehi = (_Float16*)(ws + eh_off);                   // NN*64 halves
    _Float16* elo = ehi + (size_t)NN * DOUT;
    size_t up_off = eh_off + (size_t)NN * DOUT;                 // f32 words
    _Float16* uphi = (_Float16*)(ws + up_off);
    _Float16* uplo = uphi + (size_t)NN * DOUT;
    size_t wpk_off = up_off + (size_t)NN * DOUT;
    _Float16* wpk = (_Float16*)(ws + wpk_off);                  // 688128 halves
    size_t sh_off = (wpk_off + WPK_HALVES / 2 + 3) & ~(size_t)3;
    _Float16* xpk = (_Float16*)(ws + sh_off);   // 7864320 halves (mlp phase)
    float* part = ws + sh_off;                  // 8*NN*128 f32 (prop phase)
    // xpk and part alias: xpk dead after mlp3; part born in prop6.
    // total ws footprint ~31.4 MB

    pack_all_kernel<<<dim3(1536, 8), 256, 0, stream>>>(
        W0l, W0s, W0h, W1l, W1s, W1h, ori, sm, wpk, xpk, mx);
    mlp3_kernel<<<dim3(NN / 32, 3), 256, 0, stream>>>(
        xpk, wpk, b0l, b0s, b0h, b1l, b1s, b1h, amp, ahp,
        out, emb, ehi, elo, uphi, uplo, colpart);
    max6_kernel<<<dim3(48, 48), 256, 0, stream>>>(uphi, uplo, mx);
    finalize_kernel<<<1, 64, 0, stream>>>(colpart, mx, scal);
    prop6_kernel<<<dim3(NN / 32, 8), 256, 0, stream>>>(
        uphi, uplo, ehi, elo, scal, ahp, part);
    combine4_kernel<<<NN / 16, 256, 0, stream>>>(
        part, emb, ahp, out + (size_t)2 * NN * DOUT);
}

// Round 17
// 112.998 us; speedup vs baseline: 3.5301x; 1.0592x over previous
//
#include <hip/hip_runtime.h>
#include <hip/hip_bf16.h>

#define NN 6144
#define FEATN 128
#define INSM 512
#define HIDN 256
#define DOUT 64

typedef _Float16 h4v __attribute__((ext_vector_type(4)));
typedef _Float16 h8v __attribute__((ext_vector_type(8)));
typedef float f32x4 __attribute__((ext_vector_type(4)));

// Weight-pack offsets (in halves) inside the contiguous wpk buffer.
#define O_W0L 0
#define O_W0S 65536
#define O_W0H 327680
#define O_W1L 589824
#define O_W1S 622592
#define O_W1H 655360
#define WPK_HALVES 688128
// X-pack offsets (halves) inside xpk: ori hi/lo then sm hi/lo.
#define XO_ORI 0
#define XO_SM  1572864          // 2 * 128 * 6144
#define XPK_HALVES 7864320      // + 2 * 512 * 6144

// ---------------------------------------------------------------------------
// Pack weights (ids 0-5) and X matrices (id 6 = ori, id 7 = sm) to fp16
// hi/lo in MFMA fragment k-major layout. Zeroes mx (block 0).
// ---------------------------------------------------------------------------
__global__ __launch_bounds__(256) void pack_all_kernel(
    const float* __restrict__ W0l, const float* __restrict__ W0s_,
    const float* __restrict__ W0h, const float* __restrict__ W1l,
    const float* __restrict__ W1s_, const float* __restrict__ W1h,
    const float* __restrict__ ori, const float* __restrict__ sm,
    _Float16* __restrict__ pk, _Float16* __restrict__ xpk,
    unsigned int* __restrict__ mx)
{
    const int t = threadIdx.x;
    if (blockIdx.x == 0 && blockIdx.y == 0 && t == 0) mx[0] = 0u;
    const int id = blockIdx.y;
    const int idx = blockIdx.x * 256 + t;
    if (id < 6) {
        const float* src; int K, N, offhi;
        switch (id) {
            case 0:  src = W0l;  K = 128; N = 256; offhi = O_W0L; break;
            case 1:  src = W0s_; K = 512; N = 256; offhi = O_W0S; break;
            case 2:  src = W0h;  K = 512; N = 256; offhi = O_W0H; break;
            case 3:  src = W1l;  K = 256; N = 64;  offhi = O_W1L; break;
            case 4:  src = W1s_; K = 256; N = 64;  offhi = O_W1S; break;
            default: src = W1h;  K = 256; N = 64;  offhi = O_W1H; break;
        }
        const int cnt = (K * N) >> 3;
        if (idx >= cnt) return;
        const int col  = (N == 256) ? (idx & 255) : (idx & 63);
        const int kblk = (N == 256) ? (idx >> 8) : (idx >> 6);
        h8v hi, lo;
        #pragma unroll
        for (int e = 0; e < 8; ++e) {
            float x = src[(size_t)(kblk * 8 + e) * N + col];
            _Float16 h = (_Float16)x;
            hi[e] = h;
            lo[e] = (_Float16)(x - (float)h);
        }
        *reinterpret_cast<h8v*>(&pk[(size_t)offhi + (size_t)idx * 8]) = hi;
        *reinterpret_cast<h8v*>(&pk[(size_t)offhi + (size_t)(K * N) + (size_t)idx * 8]) = lo;
    } else {
        const float* Xs = (id == 6) ? ori : sm;
        const int K = (id == 6) ? FEATN : INSM;
        const int cnt = NN * (K >> 3);
        if (idx >= cnt) return;
        const int i = idx % NN, kblk = idx / NN;
        const float* p = &Xs[(size_t)i * K + kblk * 8];
        float4 a = *reinterpret_cast<const float4*>(p);
        float4 b = *reinterpret_cast<const float4*>(p + 4);
        float fv[8] = {a.x, a.y, a.z, a.w, b.x, b.y, b.z, b.w};
        h8v hi, lo;
        #pragma unroll
        for (int e = 0; e < 8; ++e) {
            _Float16 h = (_Float16)fv[e];
            hi[e] = h;
            lo[e] = (_Float16)(fv[e] - (float)h);
        }
        _Float16* xh = xpk + ((id == 6) ? XO_ORI : XO_SM);
        _Float16* xl = xh + (size_t)K * NN;
        *reinterpret_cast<h8v*>(&xh[(size_t)idx * 8]) = hi;   // idx = kblk*NN + i
        *reinterpret_cast<h8v*>(&xl[(size_t)idx * 8]) = lo;
    }
}

// ---------------------------------------------------------------------------
// MFMA MLP v3 (proven round 14): layer-1 fragments direct from xpk; br==2
// epilogue packs ehi/elo + uphi/uplo and writes f64 column partials.
// ---------------------------------------------------------------------------
__global__ __launch_bounds__(256) void mlp3_kernel(
    const _Float16* __restrict__ xpk, const _Float16* __restrict__ pk,
    const float* __restrict__ b0l, const float* __restrict__ b0s,
    const float* __restrict__ b0h, const float* __restrict__ b1l,
    const float* __restrict__ b1s, const float* __restrict__ b1h,
    const float* __restrict__ am_p, const float* __restrict__ ah_p,
    float* __restrict__ out, float* __restrict__ emb,
    _Float16* __restrict__ ehi, _Float16* __restrict__ elo,
    _Float16* __restrict__ uphi, _Float16* __restrict__ uplo,
    double* __restrict__ colpart)
{
    __shared__ __align__(16) char smem[32 * 264 * 4];   // 33792 B
    float* hs    = (float*)smem;            // [32][264] (layer2)
    float* vals  = (float*)smem;            // [32][65] logits (br2)
    float* uvals = (float*)(smem + 16384);  // [32][65] u rows (br2)
    double* cred = (double*)(smem + 24704); // [4][64] colsum partials (br2)

    const int t = threadIdx.x;
    const int br = blockIdx.y;
    const int r0 = blockIdx.x * 32;
    const int w = t >> 6, lane = t & 63, arow = lane & 15, ag = lane >> 4;

    const _Float16 *Ahi, *Alo, *B0hi, *B0lo, *B1hi, *B1lo;
    const float *bias0, *bias1;
    int K1; float alpha;
    if (br == 0) {
        Ahi = xpk + XO_ORI; Alo = Ahi + 128 * NN;
        B0hi = pk + O_W0L; B0lo = B0hi + 128 * 256;
        B1hi = pk + O_W1L; B1lo = B1hi + 256 * 64;
        bias0 = b0l; bias1 = b1l; K1 = FEATN; alpha = am_p[0];
    } else if (br == 1) {
        Ahi = xpk + XO_SM; Alo = Ahi + 512 * NN;
        B0hi = pk + O_W0S; B0lo = B0hi + 512 * 256;
        B1hi = pk + O_W1S; B1lo = B1hi + 256 * 64;
        bias0 = b0s; bias1 = b1s; K1 = INSM; alpha = am_p[0];
    } else {
        Ahi = xpk + XO_SM; Alo = Ahi + 512 * NN;
        B0hi = pk + O_W0H; B0lo = B0hi + 512 * 256;
        B1hi = pk + O_W1H; B1lo = B1hi + 256 * 64;
        bias0 = b0h; bias1 = b1h; K1 = INSM; alpha = ah_p[0];
    }
    const int nks = K1 >> 5;

    // ---- layer 1 ----
    f32x4 acc1[2][4] = {};
    for (int ks = 0; ks < nks; ++ks) {
        h8v ahi[2], alo8[2];
        #pragma unroll
        for (int rt = 0; rt < 2; ++rt) {
            const size_t ao = ((size_t)(ks * 4 + ag) * NN + r0 + rt * 16 + arow) * 8;
            ahi[rt]  = *reinterpret_cast<const h8v*>(&Ahi[ao]);
            alo8[rt] = *reinterpret_cast<const h8v*>(&Alo[ao]);
        }
        #pragma unroll
        for (int ct = 0; ct < 4; ++ct) {
            const size_t bidx =
                ((size_t)(ks * 4 + ag) * 256 + w * 64 + ct * 16 + arow) * 8;
            h8v bhi = *reinterpret_cast<const h8v*>(&B0hi[bidx]);
            h8v blo = *reinterpret_cast<const h8v*>(&B0lo[bidx]);
            #pragma unroll
            for (int rt = 0; rt < 2; ++rt) {
                acc1[rt][ct] = __builtin_amdgcn_mfma_f32_16x16x32_f16(ahi[rt], bhi, acc1[rt][ct], 0, 0, 0);
                acc1[rt][ct] = __builtin_amdgcn_mfma_f32_16x16x32_f16(ahi[rt], blo, acc1[rt][ct], 0, 0, 0);
                acc1[rt][ct] = __builtin_amdgcn_mfma_f32_16x16x32_f16(alo8[rt], bhi, acc1[rt][ct], 0, 0, 0);
            }
        }
    }

    #pragma unroll
    for (int ct = 0; ct < 4; ++ct) {
        const int col = w * 64 + ct * 16 + arow;
        const float bb = bias0[col];
        #pragma unroll
        for (int rt = 0; rt < 2; ++rt)
            #pragma unroll
            for (int r = 0; r < 4; ++r) {
                float h = acc1[rt][ct][r] + bb;
                hs[(rt * 16 + ag * 4 + r) * 264 + col] = (h >= 0.f) ? h : alpha * h;
            }
    }
    __syncthreads();

    // ---- layer 2 ----
    f32x4 acc2[2] = {};
    #pragma unroll
    for (int ks2 = 0; ks2 < 8; ++ks2) {
        const size_t bidx = ((size_t)(ks2 * 4 + ag) * 64 + w * 16 + arow) * 8;
        h8v bhi = *reinterpret_cast<const h8v*>(&B1hi[bidx]);
        h8v blo = *reinterpret_cast<const h8v*>(&B1lo[bidx]);
        #pragma unroll
        for (int rt = 0; rt < 2; ++rt) {
            const float* ap = &hs[(rt * 16 + arow) * 264 + ks2 * 32 + ag * 8];
            float4 a = *reinterpret_cast<const float4*>(ap);
            float4 b = *reinterpret_cast<const float4*>(ap + 4);
            float fv[8] = {a.x, a.y, a.z, a.w, b.x, b.y, b.z, b.w};
            h8v ahi8, alo8;
            #pragma unroll
            for (int e = 0; e < 8; ++e) {
                _Float16 h = (_Float16)fv[e];
                ahi8[e] = h;
                alo8[e] = (_Float16)(fv[e] - (float)h);
            }
            acc2[rt] = __builtin_amdgcn_mfma_f32_16x16x32_f16(ahi8, bhi, acc2[rt], 0, 0, 0);
            acc2[rt] = __builtin_amdgcn_mfma_f32_16x16x32_f16(ahi8, blo, acc2[rt], 0, 0, 0);
            acc2[rt] = __builtin_amdgcn_mfma_f32_16x16x32_f16(alo8, bhi, acc2[rt], 0, 0, 0);
        }
    }

    const int col2 = w * 16 + arow;
    const float bb1 = bias1[col2];
    if (br < 2) {
        float* dst = out + (size_t)br * NN * DOUT;
        #pragma unroll
        for (int rt = 0; rt < 2; ++rt)
            #pragma unroll
            for (int r = 0; r < 4; ++r)
                dst[(size_t)(r0 + rt * 16 + ag * 4 + r) * 64 + col2] =
                    acc2[rt][r] + bb1;
    } else {
        __syncthreads();                        // hs reads done; vals aliases
        #pragma unroll
        for (int rt = 0; rt < 2; ++rt)
            #pragma unroll
            for (int r = 0; r < 4; ++r)
                vals[(rt * 16 + ag * 4 + r) * 65 + col2] = acc2[rt][r] + bb1;
        __syncthreads();
        double myc = 0.0;
        for (int rr = 0; rr < 8; ++rr) {
            const int row = w * 8 + rr;
            float v = vals[row * 65 + lane];
            float mv = v;
            for (int off = 32; off > 0; off >>= 1) mv = fmaxf(mv, __shfl_xor(mv, off));
            float e = expf(v - mv);
            float ssum = e;
            for (int off = 32; off > 0; off >>= 1) ssum += __shfl_xor(ssum, off);
            float s = e / ssum;
            float n2 = s * s;
            for (int off = 32; off > 0; off >>= 1) n2 += __shfl_xor(n2, off);
            float uu = s * rsqrtf(n2);    // d_i >= 1/64 so max(.,1e-9) never binds
            emb[(size_t)(r0 + row) * 64 + lane] = v;
            uvals[row * 65 + lane] = uu;
            myc += (double)uu;
        }
        cred[w * 64 + lane] = myc;
        __syncthreads();                        // uvals + cred ready; vals intact
        {   // pack ehi/elo from vals
            const int jb = t >> 6, c = t & 63;
            h8v hi, lo;
            #pragma unroll
            for (int e = 0; e < 8; ++e) {
                float x = vals[(jb * 8 + e) * 65 + c];
                _Float16 h = (_Float16)x;
                hi[e] = h;
                lo[e] = (_Float16)(x - (float)h);
            }
            const size_t o = ((size_t)(r0 / 8 + jb) * 64 + c) * 8;
            *reinterpret_cast<h8v*>(&ehi[o]) = hi;
            *reinterpret_cast<h8v*>(&elo[o]) = lo;
        }
        {   // pack uphi/uplo from uvals
            const int kb = t >> 5, i = t & 31;
            h8v hi, lo;
            #pragma unroll
            for (int e = 0; e < 8; ++e) {
                float x = uvals[i * 65 + kb * 8 + e];
                _Float16 h = (_Float16)x;
                hi[e] = h;
                lo[e] = (_Float16)(x - (float)h);
            }
            const size_t o = ((size_t)kb * NN + r0 + i) * 8;
            *reinterpret_cast<h8v*>(&uphi[o]) = hi;
            *reinterpret_cast<h8v*>(&uplo[o]) = lo;
        }
        if (t < 64) {   // per-block column partial (fixed order -> deterministic)
            double cs = cred[t] + cred[64 + t] + cred[128 + t] + cred[192 + t];
            colpart[(size_t)blockIdx.x * 64 + t] = cs;
        }
    }
}

// ---------------------------------------------------------------------------
// MFMA max pass, 128x128 tiles (grid 48x48 triangle), proven round 16.
// ---------------------------------------------------------------------------
__global__ __launch_bounds__(256) void max6_kernel(
    const _Float16* __restrict__ uphi, const _Float16* __restrict__ uplo,
    unsigned int* __restrict__ mx)
{
    const int ti = blockIdx.x, tj = blockIdx.y;
    if (tj < ti) return;
    __shared__ float red[4];
    const int t = threadIdx.x;
    const int w = t >> 6, l = t & 63, arow = l & 15, ag = l >> 4;

    f32x4 acc[8][2] = {};                     // [rowfrag][colfrag]
    #pragma unroll
    for (int ks = 0; ks < 2; ++ks) {
        h8v bhi[2], blo[2];
        #pragma unroll
        for (int cf = 0; cf < 2; ++cf) {
            const size_t bo =
                ((size_t)(ks * 4 + ag) * NN + tj * 128 + w * 32 + cf * 16 + arow) * 8;
            bhi[cf] = *reinterpret_cast<const h8v*>(&uphi[bo]);
            blo[cf] = *reinterpret_cast<const h8v*>(&uplo[bo]);
        }
        #pragma unroll
        for (int rt = 0; rt < 8; ++rt) {
            const size_t ao =
                ((size_t)(ks * 4 + ag) * NN + ti * 128 + rt * 16 + arow) * 8;
            h8v ahi_ = *reinterpret_cast<const h8v*>(&uphi[ao]);
            h8v alo_ = *reinterpret_cast<const h8v*>(&uplo[ao]);
            #pragma unroll
            for (int cf = 0; cf < 2; ++cf) {
                acc[rt][cf] = __builtin_amdgcn_mfma_f32_16x16x32_f16(ahi_, bhi[cf], acc[rt][cf], 0, 0, 0);
                acc[rt][cf] = __builtin_amdgcn_mfma_f32_16x16x32_f16(ahi_, blo[cf], acc[rt][cf], 0, 0, 0);
                acc[rt][cf] = __builtin_amdgcn_mfma_f32_16x16x32_f16(alo_, bhi[cf], acc[rt][cf], 0, 0, 0);
            }
        }
    }
    float lm = 0.f;
    #pragma unroll
    for (int rt = 0; rt < 8; ++rt)
        #pragma unroll
        for (int cf = 0; cf < 2; ++cf) {
            const int gj = tj * 128 + w * 32 + cf * 16 + arow;
            #pragma unroll
            for (int r = 0; r < 4; ++r) {
                const int gi = ti * 128 + rt * 16 + ag * 4 + r;
                if (gi != gj) lm = fmaxf(lm, acc[rt][cf][r]);
            }
        }
    for (int off = 32; off > 0; off >>= 1) lm = fmaxf(lm, __shfl_xor(lm, off));
    if ((t & 63) == 0) red[t >> 6] = lm;
    __syncthreads();
    if (t == 0) {
        float bm = fmaxf(fmaxf(red[0], red[1]), fmaxf(red[2], red[3]));
        atomicMax(mx, __float_as_uint(bm));   // all candidates > 0
    }
}

__global__ void finalize_kernel(const double* __restrict__ colpart,
                                const unsigned int* __restrict__ mx,
                                float* __restrict__ scal)
{
    const int c = threadIdx.x;   // 64 threads = 1 wave
    double cs = 0.0;
    for (int b = 0; b < 192; ++b) cs += colpart[(size_t)b * 64 + c];
    double s2 = cs * cs;
    for (int off = 32; off > 0; off >>= 1) s2 += __shfl_xor(s2, off);
    if (c == 0) {
        double md = (s2 - (double)NN) / ((double)NN * (double)NN);
        float mf = (float)md;
        float mxv = __uint_as_float(mx[0]);
        scal[0] = mf;
        scal[1] = 1.0f / (mxv - mf);
        scal[2] = 1.0f / mf;
    }
}

// ---------------------------------------------------------------------------
// Fused propagation v7: round-16 prop6 + T14 j-load prefetch. Tile t+1's
// j-side u-pack loads issue BEFORE tile t's barrier, hiding L2 latency
// under barrier + consumer MFMAs. Math bitwise-identical to prop6.
// ---------------------------------------------------------------------------
__global__ __launch_bounds__(256, 4) void prop7_kernel(
    const _Float16* __restrict__ uphi, const _Float16* __restrict__ uplo,
    const _Float16* __restrict__ ehi, const _Float16* __restrict__ elo,
    const float* __restrict__ scal, const float* __restrict__ ah_p,
    float* __restrict__ part)
{
    __shared__ __align__(16) _Float16 Abuf[2][2][32 * 128];  // 32 KB

    const int t = threadIdx.x;
    const int bi = blockIdx.x;
    const int q = blockIdx.y;
    const int gi0 = bi * 32;
    const float m = scal[0], inv_pd = scal[1], inv_m = scal[2];
    const float alpha = ah_p[0];

    const int w = t >> 6, l = t & 63, arow = l & 15, ag = l >> 4;
    const int col = w * 16 + arow;

    h8v ubhi[2][2], ublo[2][2];              // [ks][ih]
    #pragma unroll
    for (int ks = 0; ks < 2; ++ks)
        #pragma unroll
        for (int ih = 0; ih < 2; ++ih) {
            const size_t o = ((size_t)(ks * 4 + ag) * NN + gi0 + ih * 16 + arow) * 8;
            ubhi[ks][ih] = *reinterpret_cast<const h8v*>(&uphi[o]);
            ublo[ks][ih] = *reinterpret_cast<const h8v*>(&uplo[o]);
        }

    f32x4 accP[2] = {};
    f32x4 accL[2] = {};

    const int jt0 = q * 6, jt1 = jt0 + 6;

    // ---- preload j-side fragments for tile jt0 ----
    h8v jh0c[2], jl0c[2], jh1c[2], jl1c[2];   // [ff]
    #pragma unroll
    for (int ff = 0; ff < 2; ++ff) {
        const int j0 = jt0 * 128 + (w * 2 + ff) * 16;
        const size_t o0 = ((size_t)ag * NN + j0 + arow) * 8;
        jh0c[ff] = *reinterpret_cast<const h8v*>(&uphi[o0]);
        jl0c[ff] = *reinterpret_cast<const h8v*>(&uplo[o0]);
        const size_t o1 = ((size_t)(4 + ag) * NN + j0 + arow) * 8;
        jh1c[ff] = *reinterpret_cast<const h8v*>(&uphi[o1]);
        jl1c[ff] = *reinterpret_cast<const h8v*>(&uplo[o1]);
    }

    for (int jt = jt0; jt < jt1; ++jt) {
        const int buf = jt & 1;
        char* base = (char*)&Abuf[buf][0][0];
        // ---- producer: R^T fragments from preloaded j regs ----
        #pragma unroll
        for (int ff = 0; ff < 2; ++ff) {
            const int f = w * 2 + ff;
            const int j0 = jt * 128 + f * 16;
            #pragma unroll
            for (int ih = 0; ih < 2; ++ih) {
                f32x4 aR0 = {0.f, 0.f, 0.f, 0.f};
                f32x4 aR1 = {0.f, 0.f, 0.f, 0.f};
                aR0 = __builtin_amdgcn_mfma_f32_16x16x32_f16(jh0c[ff], ubhi[0][ih], aR0, 0, 0, 0);
                aR0 = __builtin_amdgcn_mfma_f32_16x16x32_f16(jh0c[ff], ublo[0][ih], aR0, 0, 0, 0);
                aR0 = __builtin_amdgcn_mfma_f32_16x16x32_f16(jl0c[ff], ubhi[0][ih], aR0, 0, 0, 0);
                aR1 = __builtin_amdgcn_mfma_f32_16x16x32_f16(jh1c[ff], ubhi[1][ih], aR1, 0, 0, 0);
                aR1 = __builtin_amdgcn_mfma_f32_16x16x32_f16(jh1c[ff], ublo[1][ih], aR1, 0, 0, 0);
                aR1 = __builtin_amdgcn_mfma_f32_16x16x32_f16(jl1c[ff], ubhi[1][ih], aR1, 0, 0, 0);
                const int gi = gi0 + ih * 16 + arow;
                h4v vh4, ph4;
                #pragma unroll
                for (int r = 0; r < 4; ++r) {
                    const int gj = j0 + ag * 4 + r;
                    float rv = aR0[r] + aR1[r];
                    float lre = (gi == gj) ? 0.f : rv;
                    float x = lre - m;
                    float v = (x > 0.f) ? x * inv_pd : -(lre * inv_m);
                    if (gi == gj) v += 1.f;          // add_diag after where
                    float p = (v >= 0.f) ? v : alpha * v;
                    vh4[r] = (_Float16)v;
                    ph4[r] = (_Float16)p;
                }
                const int gl = f * 2 + (ag >> 1);
                const int byte = (ih * 16 + arow) * 256 +
                                 ((gl ^ (arow & 15)) << 4) + ((ag & 1) << 3);
                *reinterpret_cast<h4v*>(base + byte) = vh4;
                *reinterpret_cast<h4v*>(base + 8192 + byte) = ph4;
            }
        }
        // ---- prefetch next tile's j regs (no Abuf dependency) ----
        if (jt + 1 < jt1) {
            #pragma unroll
            for (int ff = 0; ff < 2; ++ff) {
                const int j0n = (jt + 1) * 128 + (w * 2 + ff) * 16;
                const size_t o0 = ((size_t)ag * NN + j0n + arow) * 8;
                jh0c[ff] = *reinterpret_cast<const h8v*>(&uphi[o0]);
                jl0c[ff] = *reinterpret_cast<const h8v*>(&uplo[o0]);
                const size_t o1 = ((size_t)(4 + ag) * NN + j0n + arow) * 8;
                jh1c[ff] = *reinterpret_cast<const h8v*>(&uphi[o1]);
                jl1c[ff] = *reinterpret_cast<const h8v*>(&uplo[o1]);
            }
        }
        __syncthreads();        // single barrier per tile (dbuf-safe)

        // ---- consumer: P/L logit MFMAs (2-term), both i-halves ----
        const char* cbase = (const char*)&Abuf[buf][0][0];
        __builtin_amdgcn_s_setprio(1);
        #pragma unroll
        for (int ks = 0; ks < 4; ++ks) {
            const size_t bidx = ((size_t)(jt * 16 + ks * 4 + ag) * 64 + col) * 8;
            h8v Bhi = *reinterpret_cast<const h8v*>(&ehi[bidx]);
            h8v Blo = *reinterpret_cast<const h8v*>(&elo[bidx]);
            #pragma unroll
            for (int ih = 0; ih < 2; ++ih) {
                const int abyte = (ih * 16 + arow) * 256 +
                                  (((ks * 4 + ag) ^ (arow & 15)) << 4);
                h8v vhiF = *reinterpret_cast<const h8v*>(cbase + abyte);
                h8v phiF = *reinterpret_cast<const h8v*>(cbase + 8192 + abyte);
                accP[ih] = __builtin_amdgcn_mfma_f32_16x16x32_f16(phiF, Bhi, accP[ih], 0, 0, 0);
                accP[ih] = __builtin_amdgcn_mfma_f32_16x16x32_f16(phiF, Blo, accP[ih], 0, 0, 0);
                accL[ih] = __builtin_amdgcn_mfma_f32_16x16x32_f16(vhiF, Bhi, accL[ih], 0, 0, 0);
                accL[ih] = __builtin_amdgcn_mfma_f32_16x16x32_f16(vhiF, Blo, accL[ih], 0, 0, 0);
            }
        }
        __builtin_amdgcn_s_setprio(0);
    }

    {
        float* pbase = &part[((size_t)q * NN + gi0) * 128];
        #pragma unroll
        for (int ih = 0; ih < 2; ++ih)
            #pragma unroll
            for (int r = 0; r < 4; ++r) {
                const int row = ih * 16 + ag * 4 + r;
                pbase[(size_t)row * 128 + col] = accP[ih][r];
                pbase[(size_t)row * 128 + 64 + col] = accL[ih][r];
            }
    }
}

// ---------------------------------------------------------------------------
// Combine 8 partials: P = sum, L = sum, N = P - (1+alpha)L, dual softmax,
// epilogue -> out3.
// ---------------------------------------------------------------------------
__global__ __launch_bounds__(256) void combine4_kernel(
    const float* __restrict__ part, const float* __restrict__ emb,
    const float* __restrict__ ah_p, float* __restrict__ out3)
{
    const int t = threadIdx.x;
    const int w = t >> 6, l = t & 63;
    const int gi0 = blockIdx.x * 16;
    const float one_pa = 1.f + ah_p[0];
    #pragma unroll
    for (int rr = 0; rr < 4; ++rr) {
        const int gi = gi0 + w * 4 + rr;
        float zp = 0.f, zl = 0.f;
        #pragma unroll
        for (int q = 0; q < 8; ++q) {
            const float* p = &part[((size_t)q * NN + gi) * 128];
            zp += p[l];
            zl += p[64 + l];
        }
        float zn = zp - one_pa * zl;

        float mp = zp;
        for (int off = 32; off > 0; off >>= 1) mp = fmaxf(mp, __shfl_xor(mp, off));
        float ep = __expf(zp - mp);
        float sump = ep;
        for (int off = 32; off > 0; off >>= 1) sump += __shfl_xor(sump, off);
        float pp = ep / sump;

        float mn = zn;
        for (int off = 32; off > 0; off >>= 1) mn = fmaxf(mn, __shfl_xor(mn, off));
        float en = __expf(zn - mn);
        float sumn = en;
        for (int off = 32; off > 0; off >>= 1) sumn += __shfl_xor(sumn, off);
        float pn = en / sumn;

        out3[(size_t)gi * 64 + l] = 0.5f * (pp - pn + emb[(size_t)gi * 64 + l]);
    }
}

extern "C" void kernel_launch(void* const* d_in, const int* in_sizes, int n_in,
                              void* d_out, int out_size, void* d_ws, size_t ws_size,
                              hipStream_t stream)
{
    (void)in_sizes; (void)n_in; (void)out_size; (void)ws_size;
    const float* ori = (const float*)d_in[0];
    const float* sm  = (const float*)d_in[1];
    // d_in[2] processed_feature: unused; d_in[3] universal_re: unused (BETA=0)
    const float* W0s = (const float*)d_in[4];
    const float* b0s = (const float*)d_in[5];
    const float* W1s = (const float*)d_in[6];
    const float* b1s = (const float*)d_in[7];
    const float* W0l = (const float*)d_in[8];
    const float* b0l = (const float*)d_in[9];
    const float* W1l = (const float*)d_in[10];
    const float* b1l = (const float*)d_in[11];
    const float* W0h = (const float*)d_in[12];
    const float* b0h = (const float*)d_in[13];
    const float* W1h = (const float*)d_in[14];
    const float* b1h = (const float*)d_in[15];
    const float* amp = (const float*)d_in[16];
    const float* ahp = (const float*)d_in[17];

    float* out = (float*)d_out;                       // f32 output (ref dtype)
    float* ws = (float*)d_ws;
    float* emb = ws;                                            // 393216 f32
    double* colpart = (double*)(ws + (size_t)NN * DOUT);        // 192*64 f64
    unsigned int* mx = (unsigned int*)(ws + (size_t)NN * DOUT + 24576);
    float* scal = ws + (size_t)NN * DOUT + 24576 + 4;           // 3 f32
    size_t eh_off = (size_t)NN * DOUT + 24576 + 8;              // 16B-aligned
    _Float16* ehi = (_Float16*)(ws + eh_off);                   // NN*64 halves
    _Float16* elo = ehi + (size_t)NN * DOUT;
    size_t up_off = eh_off + (size_t)NN * DOUT;                 // f32 words
    _Float16* uphi = (_Float16*)(ws + up_off);
    _Float16* uplo = uphi + (size_t)NN * DOUT;
    size_t wpk_off = up_off + (size_t)NN * DOUT;
    _Float16* wpk = (_Float16*)(ws + wpk_off);                  // 688128 halves
    size_t sh_off = (wpk_off + WPK_HALVES / 2 + 3) & ~(size_t)3;
    _Float16* xpk = (_Float16*)(ws + sh_off);   // 7864320 halves (mlp phase)
    float* part = ws + sh_off;                  // 8*NN*128 f32 (prop phase)
    // xpk and part alias: xpk dead after mlp3; part born in prop7.
    // total ws footprint ~31.4 MB

    pack_all_kernel<<<dim3(1536, 8), 256, 0, stream>>>(
        W0l, W0s, W0h, W1l, W1s, W1h, ori, sm, wpk, xpk, mx);
    mlp3_kernel<<<dim3(NN / 32, 3), 256, 0, stream>>>(
        xpk, wpk, b0l, b0s, b0h, b1l, b1s, b1h, amp, ahp,
        out, emb, ehi, elo, uphi, uplo, colpart);
    max6_kernel<<<dim3(48, 48), 256, 0, stream>>>(uphi, uplo, mx);
    finalize_kernel<<<1, 64, 0, stream>>>(colpart, mx, scal);
    prop7_kernel<<<dim3(NN / 32, 8), 256, 0, stream>>>(
        uphi, uplo, ehi, elo, scal, ahp, part);
    combine4_kernel<<<NN / 16, 256, 0, stream>>>(
        part, emb, ahp, out + (size_t)2 * NN * DOUT);
}

// Round 18
// 112.691 us; speedup vs baseline: 3.5397x; 1.0027x over previous
//
#include <hip/hip_runtime.h>
#include <hip/hip_bf16.h>

#define NN 6144
#define FEATN 128
#define INSM 512
#define HIDN 256
#define DOUT 64

typedef _Float16 h4v __attribute__((ext_vector_type(4)));
typedef _Float16 h8v __attribute__((ext_vector_type(8)));
typedef float f32x4 __attribute__((ext_vector_type(4)));

// Weight-pack offsets (in halves) inside the contiguous wpk buffer.
#define O_W0L 0
#define O_W0S 65536
#define O_W0H 327680
#define O_W1L 589824
#define O_W1S 622592
#define O_W1H 655360
#define WPK_HALVES 688128
// X-pack offsets (halves) inside xpk: ori hi/lo then sm hi/lo.
#define XO_ORI 0
#define XO_SM  1572864          // 2 * 128 * 6144
#define XPK_HALVES 7864320      // + 2 * 512 * 6144

// ---------------------------------------------------------------------------
// Pack weights (ids 0-5) and X matrices (id 6 = ori, id 7 = sm) to fp16
// hi/lo in MFMA fragment k-major layout. Zeroes mx (block 0).
// ---------------------------------------------------------------------------
__global__ __launch_bounds__(256) void pack_all_kernel(
    const float* __restrict__ W0l, const float* __restrict__ W0s_,
    const float* __restrict__ W0h, const float* __restrict__ W1l,
    const float* __restrict__ W1s_, const float* __restrict__ W1h,
    const float* __restrict__ ori, const float* __restrict__ sm,
    _Float16* __restrict__ pk, _Float16* __restrict__ xpk,
    unsigned int* __restrict__ mx)
{
    const int t = threadIdx.x;
    if (blockIdx.x == 0 && blockIdx.y == 0 && t == 0) mx[0] = 0u;
    const int id = blockIdx.y;
    const int idx = blockIdx.x * 256 + t;
    if (id < 6) {
        const float* src; int K, N, offhi;
        switch (id) {
            case 0:  src = W0l;  K = 128; N = 256; offhi = O_W0L; break;
            case 1:  src = W0s_; K = 512; N = 256; offhi = O_W0S; break;
            case 2:  src = W0h;  K = 512; N = 256; offhi = O_W0H; break;
            case 3:  src = W1l;  K = 256; N = 64;  offhi = O_W1L; break;
            case 4:  src = W1s_; K = 256; N = 64;  offhi = O_W1S; break;
            default: src = W1h;  K = 256; N = 64;  offhi = O_W1H; break;
        }
        const int cnt = (K * N) >> 3;
        if (idx >= cnt) return;
        const int col  = (N == 256) ? (idx & 255) : (idx & 63);
        const int kblk = (N == 256) ? (idx >> 8) : (idx >> 6);
        h8v hi, lo;
        #pragma unroll
        for (int e = 0; e < 8; ++e) {
            float x = src[(size_t)(kblk * 8 + e) * N + col];
            _Float16 h = (_Float16)x;
            hi[e] = h;
            lo[e] = (_Float16)(x - (float)h);
        }
        *reinterpret_cast<h8v*>(&pk[(size_t)offhi + (size_t)idx * 8]) = hi;
        *reinterpret_cast<h8v*>(&pk[(size_t)offhi + (size_t)(K * N) + (size_t)idx * 8]) = lo;
    } else {
        const float* Xs = (id == 6) ? ori : sm;
        const int K = (id == 6) ? FEATN : INSM;
        const int cnt = NN * (K >> 3);
        if (idx >= cnt) return;
        const int i = idx % NN, kblk = idx / NN;
        const float* p = &Xs[(size_t)i * K + kblk * 8];
        float4 a = *reinterpret_cast<const float4*>(p);
        float4 b = *reinterpret_cast<const float4*>(p + 4);
        float fv[8] = {a.x, a.y, a.z, a.w, b.x, b.y, b.z, b.w};
        h8v hi, lo;
        #pragma unroll
        for (int e = 0; e < 8; ++e) {
            _Float16 h = (_Float16)fv[e];
            hi[e] = h;
            lo[e] = (_Float16)(fv[e] - (float)h);
        }
        _Float16* xh = xpk + ((id == 6) ? XO_ORI : XO_SM);
        _Float16* xl = xh + (size_t)K * NN;
        *reinterpret_cast<h8v*>(&xh[(size_t)idx * 8]) = hi;   // idx = kblk*NN + i
        *reinterpret_cast<h8v*>(&xl[(size_t)idx * 8]) = lo;
    }
}

// ---------------------------------------------------------------------------
// MFMA MLP v3 (proven round 14): layer-1 fragments direct from xpk; br==2
// epilogue packs ehi/elo + uphi/uplo and writes f64 column partials.
// ---------------------------------------------------------------------------
__global__ __launch_bounds__(256) void mlp3_kernel(
    const _Float16* __restrict__ xpk, const _Float16* __restrict__ pk,
    const float* __restrict__ b0l, const float* __restrict__ b0s,
    const float* __restrict__ b0h, const float* __restrict__ b1l,
    const float* __restrict__ b1s, const float* __restrict__ b1h,
    const float* __restrict__ am_p, const float* __restrict__ ah_p,
    float* __restrict__ out, float* __restrict__ emb,
    _Float16* __restrict__ ehi, _Float16* __restrict__ elo,
    _Float16* __restrict__ uphi, _Float16* __restrict__ uplo,
    double* __restrict__ colpart)
{
    __shared__ __align__(16) char smem[32 * 264 * 4];   // 33792 B
    float* hs    = (float*)smem;            // [32][264] (layer2)
    float* vals  = (float*)smem;            // [32][65] logits (br2)
    float* uvals = (float*)(smem + 16384);  // [32][65] u rows (br2)
    double* cred = (double*)(smem + 24704); // [4][64] colsum partials (br2)

    const int t = threadIdx.x;
    const int br = blockIdx.y;
    const int r0 = blockIdx.x * 32;
    const int w = t >> 6, lane = t & 63, arow = lane & 15, ag = lane >> 4;

    const _Float16 *Ahi, *Alo, *B0hi, *B0lo, *B1hi, *B1lo;
    const float *bias0, *bias1;
    int K1; float alpha;
    if (br == 0) {
        Ahi = xpk + XO_ORI; Alo = Ahi + 128 * NN;
        B0hi = pk + O_W0L; B0lo = B0hi + 128 * 256;
        B1hi = pk + O_W1L; B1lo = B1hi + 256 * 64;
        bias0 = b0l; bias1 = b1l; K1 = FEATN; alpha = am_p[0];
    } else if (br == 1) {
        Ahi = xpk + XO_SM; Alo = Ahi + 512 * NN;
        B0hi = pk + O_W0S; B0lo = B0hi + 512 * 256;
        B1hi = pk + O_W1S; B1lo = B1hi + 256 * 64;
        bias0 = b0s; bias1 = b1s; K1 = INSM; alpha = am_p[0];
    } else {
        Ahi = xpk + XO_SM; Alo = Ahi + 512 * NN;
        B0hi = pk + O_W0H; B0lo = B0hi + 512 * 256;
        B1hi = pk + O_W1H; B1lo = B1hi + 256 * 64;
        bias0 = b0h; bias1 = b1h; K1 = INSM; alpha = ah_p[0];
    }
    const int nks = K1 >> 5;

    // ---- layer 1 ----
    f32x4 acc1[2][4] = {};
    for (int ks = 0; ks < nks; ++ks) {
        h8v ahi[2], alo8[2];
        #pragma unroll
        for (int rt = 0; rt < 2; ++rt) {
            const size_t ao = ((size_t)(ks * 4 + ag) * NN + r0 + rt * 16 + arow) * 8;
            ahi[rt]  = *reinterpret_cast<const h8v*>(&Ahi[ao]);
            alo8[rt] = *reinterpret_cast<const h8v*>(&Alo[ao]);
        }
        #pragma unroll
        for (int ct = 0; ct < 4; ++ct) {
            const size_t bidx =
                ((size_t)(ks * 4 + ag) * 256 + w * 64 + ct * 16 + arow) * 8;
            h8v bhi = *reinterpret_cast<const h8v*>(&B0hi[bidx]);
            h8v blo = *reinterpret_cast<const h8v*>(&B0lo[bidx]);
            #pragma unroll
            for (int rt = 0; rt < 2; ++rt) {
                acc1[rt][ct] = __builtin_amdgcn_mfma_f32_16x16x32_f16(ahi[rt], bhi, acc1[rt][ct], 0, 0, 0);
                acc1[rt][ct] = __builtin_amdgcn_mfma_f32_16x16x32_f16(ahi[rt], blo, acc1[rt][ct], 0, 0, 0);
                acc1[rt][ct] = __builtin_amdgcn_mfma_f32_16x16x32_f16(alo8[rt], bhi, acc1[rt][ct], 0, 0, 0);
            }
        }
    }

    #pragma unroll
    for (int ct = 0; ct < 4; ++ct) {
        const int col = w * 64 + ct * 16 + arow;
        const float bb = bias0[col];
        #pragma unroll
        for (int rt = 0; rt < 2; ++rt)
            #pragma unroll
            for (int r = 0; r < 4; ++r) {
                float h = acc1[rt][ct][r] + bb;
                hs[(rt * 16 + ag * 4 + r) * 264 + col] = (h >= 0.f) ? h : alpha * h;
            }
    }
    __syncthreads();

    // ---- layer 2 ----
    f32x4 acc2[2] = {};
    #pragma unroll
    for (int ks2 = 0; ks2 < 8; ++ks2) {
        const size_t bidx = ((size_t)(ks2 * 4 + ag) * 64 + w * 16 + arow) * 8;
        h8v bhi = *reinterpret_cast<const h8v*>(&B1hi[bidx]);
        h8v blo = *reinterpret_cast<const h8v*>(&B1lo[bidx]);
        #pragma unroll
        for (int rt = 0; rt < 2; ++rt) {
            const float* ap = &hs[(rt * 16 + arow) * 264 + ks2 * 32 + ag * 8];
            float4 a = *reinterpret_cast<const float4*>(ap);
            float4 b = *reinterpret_cast<const float4*>(ap + 4);
            float fv[8] = {a.x, a.y, a.z, a.w, b.x, b.y, b.z, b.w};
            h8v ahi8, alo8;
            #pragma unroll
            for (int e = 0; e < 8; ++e) {
                _Float16 h = (_Float16)fv[e];
                ahi8[e] = h;
                alo8[e] = (_Float16)(fv[e] - (float)h);
            }
            acc2[rt] = __builtin_amdgcn_mfma_f32_16x16x32_f16(ahi8, bhi, acc2[rt], 0, 0, 0);
            acc2[rt] = __builtin_amdgcn_mfma_f32_16x16x32_f16(ahi8, blo, acc2[rt], 0, 0, 0);
            acc2[rt] = __builtin_amdgcn_mfma_f32_16x16x32_f16(alo8, bhi, acc2[rt], 0, 0, 0);
        }
    }

    const int col2 = w * 16 + arow;
    const float bb1 = bias1[col2];
    if (br < 2) {
        float* dst = out + (size_t)br * NN * DOUT;
        #pragma unroll
        for (int rt = 0; rt < 2; ++rt)
            #pragma unroll
            for (int r = 0; r < 4; ++r)
                dst[(size_t)(r0 + rt * 16 + ag * 4 + r) * 64 + col2] =
                    acc2[rt][r] + bb1;
    } else {
        __syncthreads();                        // hs reads done; vals aliases
        #pragma unroll
        for (int rt = 0; rt < 2; ++rt)
            #pragma unroll
            for (int r = 0; r < 4; ++r)
                vals[(rt * 16 + ag * 4 + r) * 65 + col2] = acc2[rt][r] + bb1;
        __syncthreads();
        double myc = 0.0;
        for (int rr = 0; rr < 8; ++rr) {
            const int row = w * 8 + rr;
            float v = vals[row * 65 + lane];
            float mv = v;
            for (int off = 32; off > 0; off >>= 1) mv = fmaxf(mv, __shfl_xor(mv, off));
            float e = expf(v - mv);
            float ssum = e;
            for (int off = 32; off > 0; off >>= 1) ssum += __shfl_xor(ssum, off);
            float s = e / ssum;
            float n2 = s * s;
            for (int off = 32; off > 0; off >>= 1) n2 += __shfl_xor(n2, off);
            float uu = s * rsqrtf(n2);    // d_i >= 1/64 so max(.,1e-9) never binds
            emb[(size_t)(r0 + row) * 64 + lane] = v;
            uvals[row * 65 + lane] = uu;
            myc += (double)uu;
        }
        cred[w * 64 + lane] = myc;
        __syncthreads();                        // uvals + cred ready; vals intact
        {   // pack ehi/elo from vals
            const int jb = t >> 6, c = t & 63;
            h8v hi, lo;
            #pragma unroll
            for (int e = 0; e < 8; ++e) {
                float x = vals[(jb * 8 + e) * 65 + c];
                _Float16 h = (_Float16)x;
                hi[e] = h;
                lo[e] = (_Float16)(x - (float)h);
            }
            const size_t o = ((size_t)(r0 / 8 + jb) * 64 + c) * 8;
            *reinterpret_cast<h8v*>(&ehi[o]) = hi;
            *reinterpret_cast<h8v*>(&elo[o]) = lo;
        }
        {   // pack uphi/uplo from uvals
            const int kb = t >> 5, i = t & 31;
            h8v hi, lo;
            #pragma unroll
            for (int e = 0; e < 8; ++e) {
                float x = uvals[i * 65 + kb * 8 + e];
                _Float16 h = (_Float16)x;
                hi[e] = h;
                lo[e] = (_Float16)(x - (float)h);
            }
            const size_t o = ((size_t)kb * NN + r0 + i) * 8;
            *reinterpret_cast<h8v*>(&uphi[o]) = hi;
            *reinterpret_cast<h8v*>(&uplo[o]) = lo;
        }
        if (t < 64) {   // per-block column partial (fixed order -> deterministic)
            double cs = cred[t] + cred[64 + t] + cred[128 + t] + cred[192 + t];
            colpart[(size_t)blockIdx.x * 64 + t] = cs;
        }
    }
}

// ---------------------------------------------------------------------------
// MFMA max pass, 128x128 tiles (grid 48x48 triangle), proven round 16.
// ---------------------------------------------------------------------------
__global__ __launch_bounds__(256) void max6_kernel(
    const _Float16* __restrict__ uphi, const _Float16* __restrict__ uplo,
    unsigned int* __restrict__ mx)
{
    const int ti = blockIdx.x, tj = blockIdx.y;
    if (tj < ti) return;
    __shared__ float red[4];
    const int t = threadIdx.x;
    const int w = t >> 6, l = t & 63, arow = l & 15, ag = l >> 4;

    f32x4 acc[8][2] = {};                     // [rowfrag][colfrag]
    #pragma unroll
    for (int ks = 0; ks < 2; ++ks) {
        h8v bhi[2], blo[2];
        #pragma unroll
        for (int cf = 0; cf < 2; ++cf) {
            const size_t bo =
                ((size_t)(ks * 4 + ag) * NN + tj * 128 + w * 32 + cf * 16 + arow) * 8;
            bhi[cf] = *reinterpret_cast<const h8v*>(&uphi[bo]);
            blo[cf] = *reinterpret_cast<const h8v*>(&uplo[bo]);
        }
        #pragma unroll
        for (int rt = 0; rt < 8; ++rt) {
            const size_t ao =
                ((size_t)(ks * 4 + ag) * NN + ti * 128 + rt * 16 + arow) * 8;
            h8v ahi_ = *reinterpret_cast<const h8v*>(&uphi[ao]);
            h8v alo_ = *reinterpret_cast<const h8v*>(&uplo[ao]);
            #pragma unroll
            for (int cf = 0; cf < 2; ++cf) {
                acc[rt][cf] = __builtin_amdgcn_mfma_f32_16x16x32_f16(ahi_, bhi[cf], acc[rt][cf], 0, 0, 0);
                acc[rt][cf] = __builtin_amdgcn_mfma_f32_16x16x32_f16(ahi_, blo[cf], acc[rt][cf], 0, 0, 0);
                acc[rt][cf] = __builtin_amdgcn_mfma_f32_16x16x32_f16(alo_, bhi[cf], acc[rt][cf], 0, 0, 0);
            }
        }
    }
    float lm = 0.f;
    #pragma unroll
    for (int rt = 0; rt < 8; ++rt)
        #pragma unroll
        for (int cf = 0; cf < 2; ++cf) {
            const int gj = tj * 128 + w * 32 + cf * 16 + arow;
            #pragma unroll
            for (int r = 0; r < 4; ++r) {
                const int gi = ti * 128 + rt * 16 + ag * 4 + r;
                if (gi != gj) lm = fmaxf(lm, acc[rt][cf][r]);
            }
        }
    for (int off = 32; off > 0; off >>= 1) lm = fmaxf(lm, __shfl_xor(lm, off));
    if ((t & 63) == 0) red[t >> 6] = lm;
    __syncthreads();
    if (t == 0) {
        float bm = fmaxf(fmaxf(red[0], red[1]), fmaxf(red[2], red[3]));
        atomicMax(mx, __float_as_uint(bm));   // all candidates > 0
    }
}

__global__ void finalize_kernel(const double* __restrict__ colpart,
                                const unsigned int* __restrict__ mx,
                                float* __restrict__ scal)
{
    const int c = threadIdx.x;   // 64 threads = 1 wave
    double cs = 0.0;
    for (int b = 0; b < 192; ++b) cs += colpart[(size_t)b * 64 + c];
    double s2 = cs * cs;
    for (int off = 32; off > 0; off >>= 1) s2 += __shfl_xor(s2, off);
    if (c == 0) {
        double md = (s2 - (double)NN) / ((double)NN * (double)NN);
        float mf = (float)md;
        float mxv = __uint_as_float(mx[0]);
        scal[0] = mf;
        scal[1] = 1.0f / (mxv - mf);
        scal[2] = 1.0f / mf;
    }
}

// ---------------------------------------------------------------------------
// Fused propagation v8: prop7 + (a) grid dims swapped to (q=8, bi=192) so
// consecutive block-ids differ in q -> XCD round-robin pins one q-slice
// (~1 MB of u/e pack) per XCD L2 (was ~6 MB thrash); (b) consumer's e-side
// B-frags for ks=0,1 prefetched pre-barrier. Math bitwise-identical.
// ---------------------------------------------------------------------------
__global__ __launch_bounds__(256, 4) void prop8_kernel(
    const _Float16* __restrict__ uphi, const _Float16* __restrict__ uplo,
    const _Float16* __restrict__ ehi, const _Float16* __restrict__ elo,
    const float* __restrict__ scal, const float* __restrict__ ah_p,
    float* __restrict__ part)
{
    __shared__ __align__(16) _Float16 Abuf[2][2][32 * 128];  // 32 KB

    const int t = threadIdx.x;
    const int q = blockIdx.x;               // swapped: q fastest -> XCD-clustered
    const int bi = blockIdx.y;
    const int gi0 = bi * 32;
    const float m = scal[0], inv_pd = scal[1], inv_m = scal[2];
    const float alpha = ah_p[0];

    const int w = t >> 6, l = t & 63, arow = l & 15, ag = l >> 4;
    const int col = w * 16 + arow;

    h8v ubhi[2][2], ublo[2][2];              // [ks][ih]
    #pragma unroll
    for (int ks = 0; ks < 2; ++ks)
        #pragma unroll
        for (int ih = 0; ih < 2; ++ih) {
            const size_t o = ((size_t)(ks * 4 + ag) * NN + gi0 + ih * 16 + arow) * 8;
            ubhi[ks][ih] = *reinterpret_cast<const h8v*>(&uphi[o]);
            ublo[ks][ih] = *reinterpret_cast<const h8v*>(&uplo[o]);
        }

    f32x4 accP[2] = {};
    f32x4 accL[2] = {};

    const int jt0 = q * 6, jt1 = jt0 + 6;

    // ---- preload j-side fragments for tile jt0 ----
    h8v jh0c[2], jl0c[2], jh1c[2], jl1c[2];   // [ff]
    #pragma unroll
    for (int ff = 0; ff < 2; ++ff) {
        const int j0 = jt0 * 128 + (w * 2 + ff) * 16;
        const size_t o0 = ((size_t)ag * NN + j0 + arow) * 8;
        jh0c[ff] = *reinterpret_cast<const h8v*>(&uphi[o0]);
        jl0c[ff] = *reinterpret_cast<const h8v*>(&uplo[o0]);
        const size_t o1 = ((size_t)(4 + ag) * NN + j0 + arow) * 8;
        jh1c[ff] = *reinterpret_cast<const h8v*>(&uphi[o1]);
        jl1c[ff] = *reinterpret_cast<const h8v*>(&uplo[o1]);
    }

    for (int jt = jt0; jt < jt1; ++jt) {
        const int buf = jt & 1;
        char* base = (char*)&Abuf[buf][0][0];
        // ---- producer: R^T fragments from preloaded j regs ----
        #pragma unroll
        for (int ff = 0; ff < 2; ++ff) {
            const int f = w * 2 + ff;
            const int j0 = jt * 128 + f * 16;
            #pragma unroll
            for (int ih = 0; ih < 2; ++ih) {
                f32x4 aR0 = {0.f, 0.f, 0.f, 0.f};
                f32x4 aR1 = {0.f, 0.f, 0.f, 0.f};
                aR0 = __builtin_amdgcn_mfma_f32_16x16x32_f16(jh0c[ff], ubhi[0][ih], aR0, 0, 0, 0);
                aR0 = __builtin_amdgcn_mfma_f32_16x16x32_f16(jh0c[ff], ublo[0][ih], aR0, 0, 0, 0);
                aR0 = __builtin_amdgcn_mfma_f32_16x16x32_f16(jl0c[ff], ubhi[0][ih], aR0, 0, 0, 0);
                aR1 = __builtin_amdgcn_mfma_f32_16x16x32_f16(jh1c[ff], ubhi[1][ih], aR1, 0, 0, 0);
                aR1 = __builtin_amdgcn_mfma_f32_16x16x32_f16(jh1c[ff], ublo[1][ih], aR1, 0, 0, 0);
                aR1 = __builtin_amdgcn_mfma_f32_16x16x32_f16(jl1c[ff], ubhi[1][ih], aR1, 0, 0, 0);
                const int gi = gi0 + ih * 16 + arow;
                h4v vh4, ph4;
                #pragma unroll
                for (int r = 0; r < 4; ++r) {
                    const int gj = j0 + ag * 4 + r;
                    float rv = aR0[r] + aR1[r];
                    float lre = (gi == gj) ? 0.f : rv;
                    float x = lre - m;
                    float v = (x > 0.f) ? x * inv_pd : -(lre * inv_m);
                    if (gi == gj) v += 1.f;          // add_diag after where
                    float p = (v >= 0.f) ? v : alpha * v;
                    vh4[r] = (_Float16)v;
                    ph4[r] = (_Float16)p;
                }
                const int gl = f * 2 + (ag >> 1);
                const int byte = (ih * 16 + arow) * 256 +
                                 ((gl ^ (arow & 15)) << 4) + ((ag & 1) << 3);
                *reinterpret_cast<h4v*>(base + byte) = vh4;
                *reinterpret_cast<h4v*>(base + 8192 + byte) = ph4;
            }
        }
        // ---- prefetch next tile's j regs (no Abuf dependency) ----
        if (jt + 1 < jt1) {
            #pragma unroll
            for (int ff = 0; ff < 2; ++ff) {
                const int j0n = (jt + 1) * 128 + (w * 2 + ff) * 16;
                const size_t o0 = ((size_t)ag * NN + j0n + arow) * 8;
                jh0c[ff] = *reinterpret_cast<const h8v*>(&uphi[o0]);
                jl0c[ff] = *reinterpret_cast<const h8v*>(&uplo[o0]);
                const size_t o1 = ((size_t)(4 + ag) * NN + j0n + arow) * 8;
                jh1c[ff] = *reinterpret_cast<const h8v*>(&uphi[o1]);
                jl1c[ff] = *reinterpret_cast<const h8v*>(&uplo[o1]);
            }
        }
        // ---- prefetch this tile's e B-frags for ks=0,1 (used post-barrier) ----
        h8v eBhi[2], eBlo[2];
        #pragma unroll
        for (int ks = 0; ks < 2; ++ks) {
            const size_t bidx = ((size_t)(jt * 16 + ks * 4 + ag) * 64 + col) * 8;
            eBhi[ks] = *reinterpret_cast<const h8v*>(&ehi[bidx]);
            eBlo[ks] = *reinterpret_cast<const h8v*>(&elo[bidx]);
        }
        __syncthreads();        // single barrier per tile (dbuf-safe)

        // ---- consumer: P/L logit MFMAs (2-term), both i-halves ----
        const char* cbase = (const char*)&Abuf[buf][0][0];
        __builtin_amdgcn_s_setprio(1);
        #pragma unroll
        for (int ks = 0; ks < 4; ++ks) {
            h8v Bhi, Blo;
            if (ks < 2) { Bhi = eBhi[ks]; Blo = eBlo[ks]; }
            else {
                const size_t bidx = ((size_t)(jt * 16 + ks * 4 + ag) * 64 + col) * 8;
                Bhi = *reinterpret_cast<const h8v*>(&ehi[bidx]);
                Blo = *reinterpret_cast<const h8v*>(&elo[bidx]);
            }
            #pragma unroll
            for (int ih = 0; ih < 2; ++ih) {
                const int abyte = (ih * 16 + arow) * 256 +
                                  (((ks * 4 + ag) ^ (arow & 15)) << 4);
                h8v vhiF = *reinterpret_cast<const h8v*>(cbase + abyte);
                h8v phiF = *reinterpret_cast<const h8v*>(cbase + 8192 + abyte);
                accP[ih] = __builtin_amdgcn_mfma_f32_16x16x32_f16(phiF, Bhi, accP[ih], 0, 0, 0);
                accP[ih] = __builtin_amdgcn_mfma_f32_16x16x32_f16(phiF, Blo, accP[ih], 0, 0, 0);
                accL[ih] = __builtin_amdgcn_mfma_f32_16x16x32_f16(vhiF, Bhi, accL[ih], 0, 0, 0);
                accL[ih] = __builtin_amdgcn_mfma_f32_16x16x32_f16(vhiF, Blo, accL[ih], 0, 0, 0);
            }
        }
        __builtin_amdgcn_s_setprio(0);
    }

    {
        float* pbase = &part[((size_t)q * NN + gi0) * 128];
        #pragma unroll
        for (int ih = 0; ih < 2; ++ih)
            #pragma unroll
            for (int r = 0; r < 4; ++r) {
                const int row = ih * 16 + ag * 4 + r;
                pbase[(size_t)row * 128 + col] = accP[ih][r];
                pbase[(size_t)row * 128 + 64 + col] = accL[ih][r];
            }
    }
}

// ---------------------------------------------------------------------------
// Combine 8 partials: P = sum, L = sum, N = P - (1+alpha)L, dual softmax,
// epilogue -> out3.
// ---------------------------------------------------------------------------
__global__ __launch_bounds__(256) void combine4_kernel(
    const float* __restrict__ part, const float* __restrict__ emb,
    const float* __restrict__ ah_p, float* __restrict__ out3)
{
    const int t = threadIdx.x;
    const int w = t >> 6, l = t & 63;
    const int gi0 = blockIdx.x * 16;
    const float one_pa = 1.f + ah_p[0];
    #pragma unroll
    for (int rr = 0; rr < 4; ++rr) {
        const int gi = gi0 + w * 4 + rr;
        float zp = 0.f, zl = 0.f;
        #pragma unroll
        for (int q = 0; q < 8; ++q) {
            const float* p = &part[((size_t)q * NN + gi) * 128];
            zp += p[l];
            zl += p[64 + l];
        }
        float zn = zp - one_pa * zl;

        float mp = zp;
        for (int off = 32; off > 0; off >>= 1) mp = fmaxf(mp, __shfl_xor(mp, off));
        float ep = __expf(zp - mp);
        float sump = ep;
        for (int off = 32; off > 0; off >>= 1) sump += __shfl_xor(sump, off);
        float pp = ep / sump;

        float mn = zn;
        for (int off = 32; off > 0; off >>= 1) mn = fmaxf(mn, __shfl_xor(mn, off));
        float en = __expf(zn - mn);
        float sumn = en;
        for (int off = 32; off > 0; off >>= 1) sumn += __shfl_xor(sumn, off);
        float pn = en / sumn;

        out3[(size_t)gi * 64 + l] = 0.5f * (pp - pn + emb[(size_t)gi * 64 + l]);
    }
}

extern "C" void kernel_launch(void* const* d_in, const int* in_sizes, int n_in,
                              void* d_out, int out_size, void* d_ws, size_t ws_size,
                              hipStream_t stream)
{
    (void)in_sizes; (void)n_in; (void)out_size; (void)ws_size;
    const float* ori = (const float*)d_in[0];
    const float* sm  = (const float*)d_in[1];
    // d_in[2] processed_feature: unused; d_in[3] universal_re: unused (BETA=0)
    const float* W0s = (const float*)d_in[4];
    const float* b0s = (const float*)d_in[5];
    const float* W1s = (const float*)d_in[6];
    const float* b1s = (const float*)d_in[7];
    const float* W0l = (const float*)d_in[8];
    const float* b0l = (const float*)d_in[9];
    const float* W1l = (const float*)d_in[10];
    const float* b1l = (const float*)d_in[11];
    const float* W0h = (const float*)d_in[12];
    const float* b0h = (const float*)d_in[13];
    const float* W1h = (const float*)d_in[14];
    const float* b1h = (const float*)d_in[15];
    const float* amp = (const float*)d_in[16];
    const float* ahp = (const float*)d_in[17];

    float* out = (float*)d_out;                       // f32 output (ref dtype)
    float* ws = (float*)d_ws;
    float* emb = ws;                                            // 393216 f32
    double* colpart = (double*)(ws + (size_t)NN * DOUT);        // 192*64 f64
    unsigned int* mx = (unsigned int*)(ws + (size_t)NN * DOUT + 24576);
    float* scal = ws + (size_t)NN * DOUT + 24576 + 4;           // 3 f32
    size_t eh_off = (size_t)NN * DOUT + 24576 + 8;              // 16B-aligned
    _Float16* ehi = (_Float16*)(ws + eh_off);                   // NN*64 halves
    _Float16* elo = ehi + (size_t)NN * DOUT;
    size_t up_off = eh_off + (size_t)NN * DOUT;                 // f32 words
    _Float16* uphi = (_Float16*)(ws + up_off);
    _Float16* uplo = uphi + (size_t)NN * DOUT;
    size_t wpk_off = up_off + (size_t)NN * DOUT;
    _Float16* wpk = (_Float16*)(ws + wpk_off);                  // 688128 halves
    size_t sh_off = (wpk_off + WPK_HALVES / 2 + 3) & ~(size_t)3;
    _Float16* xpk = (_Float16*)(ws + sh_off);   // 7864320 halves (mlp phase)
    float* part = ws + sh_off;                  // 8*NN*128 f32 (prop phase)
    // xpk and part alias: xpk dead after mlp3; part born in prop8.
    // total ws footprint ~31.4 MB

    pack_all_kernel<<<dim3(1536, 8), 256, 0, stream>>>(
        W0l, W0s, W0h, W1l, W1s, W1h, ori, sm, wpk, xpk, mx);
    mlp3_kernel<<<dim3(NN / 32, 3), 256, 0, stream>>>(
        xpk, wpk, b0l, b0s, b0h, b1l, b1s, b1h, amp, ahp,
        out, emb, ehi, elo, uphi, uplo, colpart);
    max6_kernel<<<dim3(48, 48), 256, 0, stream>>>(uphi, uplo, mx);
    finalize_kernel<<<1, 64, 0, stream>>>(colpart, mx, scal);
    prop8_kernel<<<dim3(8, NN / 32), 256, 0, stream>>>(
        uphi, uplo, ehi, elo, scal, ahp, part);
    combine4_kernel<<<NN / 16, 256, 0, stream>>>(
        part, emb, ahp, out + (size_t)2 * NN * DOUT);
}